// Round 1
// baseline (1013.106 us; speedup 1.0000x reference)
//
#include <hip/hip_runtime.h>
#include <math.h>

typedef __attribute__((ext_vector_type(8))) short s8v;   // 8 x bf16
typedef __attribute__((ext_vector_type(4))) short s4v;   // 4 x bf16
typedef __attribute__((ext_vector_type(4))) float f4v;   // 4 x f32
typedef __attribute__((ext_vector_type(16))) float f16v; // 16 x f32

static __device__ __forceinline__ unsigned short f2bf(float f) {
    union { float f; unsigned int u; } v; v.f = f;
    unsigned int r = v.u + 0x7fffu + ((v.u >> 16) & 1u);   // RNE
    return (unsigned short)(r >> 16);
}
static __device__ __forceinline__ float bf2f(unsigned short h) {
    union { unsigned int u; float f; } t; t.u = ((unsigned int)h) << 16;
    return t.f;
}

// ---------- split all weights to bf16 hi/lo planes ----------
// layout: [Win(32768) | Wh0 | Wh1 | Wh2 (262144 each) | Wout(32768)] = 851968
__global__ void conv_split(const float* __restrict__ Win, const float* __restrict__ Wh,
                           const float* __restrict__ Wout,
                           unsigned short* __restrict__ whi, unsigned short* __restrict__ wlo) {
    int i = blockIdx.x * 256 + threadIdx.x;
    if (i >= 851968) return;
    float v;
    if (i < 32768)       v = Win[i];
    else if (i < 819200) v = Wh[i - 32768];
    else                 v = Wout[i - 819200];
    unsigned short h = f2bf(v);
    whi[i] = h;
    wlo[i] = f2bf(v - bf2f(h));
}

// ---------- G0 = Wh0 @ W_in (512x64): hi/lo planes + transposed hi for zng ----------
__global__ void g0_kernel(const float* __restrict__ Wh0, const float* __restrict__ Win,
                          unsigned short* __restrict__ G0hi, unsigned short* __restrict__ G0lo,
                          unsigned short* __restrict__ G0tb) {
    int i = blockIdx.x;      // 0..511
    int j = threadIdx.x;     // 0..63
    float acc = 0.f;
    for (int k = 0; k < 512; ++k)
        acc = fmaf(Wh0[i * 512 + k], Win[k * 64 + j], acc);
    unsigned short h = f2bf(acc);
    G0hi[i * 64 + j] = h;
    G0lo[i * 64 + j] = f2bf(acc - bf2f(h));
    G0tb[j * 512 + i] = h;
}

// ======== dual GEMM, 512 threads (R13-validated): z=0 fp32 4x4 micro (t branch);
//          z=1 split-bf16 MFMA, 8 waves of 32x32 (z branch, flip-tolerant).
__global__ __launch_bounds__(512) void gemm_dual(
    const float* __restrict__ X0, const float* __restrict__ X1, int ldx,
    const float* __restrict__ W, int ldw,
    const unsigned short* __restrict__ Whi, const unsigned short* __restrict__ Wlo,
    const float* __restrict__ bias,
    float* __restrict__ C0, float* __restrict__ C1, int ldc,
    unsigned char* __restrict__ mo0, unsigned char* __restrict__ mo1,
    const unsigned char* __restrict__ mm0, const unsigned char* __restrict__ mm1,
    int K, int N, int mode)
{
    __shared__ __align__(16) unsigned char lds[30720];
    const int tid = threadIdx.x;
    const int m0 = blockIdx.x * 128;
    const int n0 = blockIdx.y * 64;

    if (blockIdx.z == 0) {
        // ---------------- fp32 vector path, 4x4 micro ----------------
        const float* __restrict__ X = X0;
        float* __restrict__ C = C0;
        unsigned char* __restrict__ maskOut = mo0;
        const unsigned char* __restrict__ maskMul = mm0;
        float (*Xs)[132] = (float(*)[132])lds;                 // 16896 B
        float (*Ws)[68]  = (float(*)[68])(lds + 16896);        // 8704 B
        const int tx = tid & 15, ty = tid >> 4;                // ty 0..31
        float acc[4][4] = {};
        float4 xr[2], wr;

        #define LOADF(k0)                                                            \
            {                                                                        \
                _Pragma("unroll")                                                    \
                for (int r = 0; r < 2; ++r) {                                        \
                    int idx = tid + r * 512;                                         \
                    int row = idx >> 3, kq = (idx & 7) * 4;                          \
                    xr[r] = *(const float4*)(X + (size_t)(m0 + row) * ldx + (k0) + kq); \
                }                                                                    \
                {                                                                    \
                    int row = tid >> 3, kq = (tid & 7) * 4;                          \
                    wr = *(const float4*)(W + (size_t)(n0 + row) * ldw + (k0) + kq); \
                }                                                                    \
            }
        #define STASHF()                                                             \
            {                                                                        \
                _Pragma("unroll")                                                    \
                for (int r = 0; r < 2; ++r) {                                        \
                    int idx = tid + r * 512;                                         \
                    int row = idx >> 3, kq = (idx & 7) * 4;                          \
                    Xs[kq + 0][row] = xr[r].x; Xs[kq + 1][row] = xr[r].y;            \
                    Xs[kq + 2][row] = xr[r].z; Xs[kq + 3][row] = xr[r].w;            \
                }                                                                    \
                {                                                                    \
                    int row = tid >> 3, kq = (tid & 7) * 4;                          \
                    Ws[kq + 0][row] = wr.x; Ws[kq + 1][row] = wr.y;                  \
                    Ws[kq + 2][row] = wr.z; Ws[kq + 3][row] = wr.w;                  \
                }                                                                    \
            }

        LOADF(0);
        STASHF();
        __syncthreads();

        for (int k0 = 0; k0 < K; k0 += 32) {
            bool last = (k0 + 32 >= K);
            if (!last) LOADF(k0 + 32);
            #pragma unroll
            for (int kk = 0; kk < 32; ++kk) {
                float4 a0 = *(const float4*)&Xs[kk][ty * 4];
                float4 b0 = *(const float4*)&Ws[kk][tx * 4];
                float av[4] = {a0.x, a0.y, a0.z, a0.w};
                float bv[4] = {b0.x, b0.y, b0.z, b0.w};
                #pragma unroll
                for (int i = 0; i < 4; ++i)
                    #pragma unroll
                    for (int j = 0; j < 4; ++j)
                        acc[i][j] = fmaf(av[i], bv[j], acc[i][j]);
            }
            __syncthreads();
            if (!last) {
                STASHF();
                __syncthreads();
            }
        }

        float4 bb = {0, 0, 0, 0};
        if (mode & 1) bb = *(const float4*)(bias + n0 + tx * 4);
        const int c0 = n0 + tx * 4;
        #pragma unroll
        for (int i = 0; i < 4; ++i) {
            int r = m0 + ty * 4 + i;
            float v[4];
            #pragma unroll
            for (int j = 0; j < 4; ++j) {
                v[j] = acc[i][j];
                if (mode & 1) v[j] += ((const float*)&bb)[j];
            }
            if (mode & 8) {
                uchar4 mo;
                mo.x = v[0] > 0.0f; mo.y = v[1] > 0.0f; mo.z = v[2] > 0.0f; mo.w = v[3] > 0.0f;
                *(uchar4*)&maskOut[(size_t)r * N + c0] = mo;
            }
            if (mode & 16) {
                uchar4 mm = *(const uchar4*)&maskMul[(size_t)r * N + c0];
                v[0] *= mm.x; v[1] *= mm.y; v[2] *= mm.z; v[3] *= mm.w;
            }
            if (mode & 2) {
                #pragma unroll
                for (int j = 0; j < 4; ++j) v[j] = fmaxf(v[j], 0.0f);
            }
            if (mode & 4) {
                float4 st = {v[0], v[1], v[2], v[3]};
                *(float4*)(C + (size_t)r * ldc + c0) = st;
            }
        }
    } else {
        // ---------------- split-bf16 MFMA path, 8 waves of 32x32 ----------------
        const float* __restrict__ X = X1;
        float* __restrict__ C = C1;
        unsigned char* __restrict__ maskOut = mo1;
        const unsigned char* __restrict__ maskMul = mm1;
        unsigned short* Xh  = (unsigned short*)lds;            // 128*40 = 10240 B
        unsigned short* Xl  = (unsigned short*)(lds + 10240);  // 10240 B
        unsigned short* Wsh = (unsigned short*)(lds + 20480);  // 5120 B
        unsigned short* Wsl = (unsigned short*)(lds + 25600);  // 5120 B

        const int wave = tid >> 6, lane = tid & 63;
        const int q = lane >> 4, ln = lane & 15;
        const int wm = (wave & 3) * 32;      // m-offset (0..96)
        const int wn = (wave >> 2) * 32;     // n-offset (0/32)

        f4v acc[2][2];
        #pragma unroll
        for (int mt = 0; mt < 2; ++mt)
            #pragma unroll
            for (int nt = 0; nt < 2; ++nt)
                acc[mt][nt] = (f4v)(0.0f);

        float4 xr[2];
        s8v wh, wl;
        const bool wload = (tid < 256);

        #define LOADD(k0)                                                              \
            {                                                                          \
                _Pragma("unroll")                                                      \
                for (int r = 0; r < 2; ++r) {                                          \
                    int idx = tid + r * 512;                                           \
                    int row = idx >> 3, kq = (idx & 7) * 4;                            \
                    xr[r] = *(const float4*)(X + (size_t)(m0 + row) * ldx + (k0) + kq); \
                }                                                                      \
                if (wload) {                                                           \
                    int row = tid >> 2, kc = (tid & 3) * 8;                            \
                    wh = *(const s8v*)(Whi + (size_t)(n0 + row) * ldw + (k0) + kc);    \
                    wl = *(const s8v*)(Wlo + (size_t)(n0 + row) * ldw + (k0) + kc);    \
                }                                                                      \
            }
        #define STASHD()                                                               \
            {                                                                          \
                _Pragma("unroll")                                                      \
                for (int r = 0; r < 2; ++r) {                                          \
                    int idx = tid + r * 512;                                           \
                    int row = idx >> 3, kq = (idx & 7) * 4;                            \
                    float a[4] = {xr[r].x, xr[r].y, xr[r].z, xr[r].w};                 \
                    s4v hv, lv;                                                        \
                    _Pragma("unroll")                                                  \
                    for (int j = 0; j < 4; ++j) {                                      \
                        unsigned short h = f2bf(a[j]);                                 \
                        hv[j] = (short)h;                                              \
                        lv[j] = (short)f2bf(a[j] - bf2f(h));                           \
                    }                                                                  \
                    *(s4v*)&Xh[row * 40 + kq] = hv;                                    \
                    *(s4v*)&Xl[row * 40 + kq] = lv;                                    \
                }                                                                      \
                if (wload) {                                                           \
                    int row = tid >> 2, kc = (tid & 3) * 8;                            \
                    *(s8v*)&Wsh[row * 40 + kc] = wh;                                   \
                    *(s8v*)&Wsl[row * 40 + kc] = wl;                                   \
                }                                                                      \
            }

        LOADD(0);
        STASHD();
        __syncthreads();

        for (int k0 = 0; k0 < K; k0 += 32) {
            bool last = (k0 + 32 >= K);
            if (!last) LOADD(k0 + 32);

            s8v ah[2], al[2], bh[2], bl[2];
            #pragma unroll
            for (int mt = 0; mt < 2; ++mt) {
                int rowm = wm + mt * 16 + ln;
                ah[mt] = *(const s8v*)&Xh[rowm * 40 + q * 8];
                al[mt] = *(const s8v*)&Xl[rowm * 40 + q * 8];
            }
            #pragma unroll
            for (int nt = 0; nt < 2; ++nt) {
                int rown = wn + nt * 16 + ln;
                bh[nt] = *(const s8v*)&Wsh[rown * 40 + q * 8];
                bl[nt] = *(const s8v*)&Wsl[rown * 40 + q * 8];
            }
            #pragma unroll
            for (int mt = 0; mt < 2; ++mt)
                #pragma unroll
                for (int nt = 0; nt < 2; ++nt) {
                    acc[mt][nt] = __builtin_amdgcn_mfma_f32_16x16x32_bf16(ah[mt], bh[nt], acc[mt][nt], 0, 0, 0);
                    acc[mt][nt] = __builtin_amdgcn_mfma_f32_16x16x32_bf16(ah[mt], bl[nt], acc[mt][nt], 0, 0, 0);
                    acc[mt][nt] = __builtin_amdgcn_mfma_f32_16x16x32_bf16(al[mt], bh[nt], acc[mt][nt], 0, 0, 0);
                }

            __syncthreads();
            if (!last) {
                STASHD();
                __syncthreads();
            }
        }

        // epilogue: C-layout col=lane&15, row=q*4+r (m89-verified)
        #pragma unroll
        for (int nt = 0; nt < 2; ++nt) {
            int n = n0 + wn + nt * 16 + ln;
            float bv = (mode & 1) ? bias[n] : 0.0f;
            #pragma unroll
            for (int mt = 0; mt < 2; ++mt) {
                int mbase = m0 + wm + mt * 16 + q * 4;
                #pragma unroll
                for (int r = 0; r < 4; ++r) {
                    int m = mbase + r;
                    float v = acc[mt][nt][r] + bv;
                    if (mode & 8)  maskOut[(size_t)m * N + n] = (v > 0.0f) ? 1 : 0;
                    if (mode & 16) v *= (float)maskMul[(size_t)m * N + n];
                    if (mode & 2)  v = fmaxf(v, 0.0f);
                    if (mode & 4)  C[(size_t)m * ldc + n] = v;
                }
            }
        }
    }
}

// ======== fp32 GEMM 128x64 (R4-validated) — t-branch finals ========
__global__ __launch_bounds__(256) void gemm_nt(
    const float* __restrict__ X, int ldx,
    const float* __restrict__ W, int ldw,
    const float* __restrict__ bias,
    float* __restrict__ C, int ldc,
    unsigned char* __restrict__ maskOut,
    const unsigned char* __restrict__ maskMul,
    int K, int N, int mode)
{
    __shared__ float Xs[32][132];
    __shared__ float Ws[32][68];
    const int tid = threadIdx.x;
    const int m0 = blockIdx.x * 128;
    const int n0 = blockIdx.y * 64;
    const int tx = tid & 15, ty = tid >> 4;
    float acc[8][4] = {};
    float4 xr[4], wr[2];

    #define LOADCHUNK(k0)                                                        \
        {                                                                        \
            _Pragma("unroll")                                                    \
            for (int r = 0; r < 4; ++r) {                                        \
                int idx = tid + r * 256;                                         \
                int row = idx >> 3, kq = (idx & 7) * 4;                          \
                xr[r] = *(const float4*)(X + (size_t)(m0 + row) * ldx + (k0) + kq); \
            }                                                                    \
            _Pragma("unroll")                                                    \
            for (int r = 0; r < 2; ++r) {                                        \
                int idx = tid + r * 256;                                         \
                int row = idx >> 3, kq = (idx & 7) * 4;                          \
                wr[r] = *(const float4*)(W + (size_t)(n0 + row) * ldw + (k0) + kq); \
            }                                                                    \
        }
    #define STASH()                                                              \
        {                                                                        \
            _Pragma("unroll")                                                    \
            for (int r = 0; r < 4; ++r) {                                        \
                int idx = tid + r * 256;                                         \
                int row = idx >> 3, kq = (idx & 7) * 4;                          \
                Xs[kq + 0][row] = xr[r].x; Xs[kq + 1][row] = xr[r].y;            \
                Xs[kq + 2][row] = xr[r].z; Xs[kq + 3][row] = xr[r].w;            \
            }                                                                    \
            _Pragma("unroll")                                                    \
            for (int r = 0; r < 2; ++r) {                                        \
                int idx = tid + r * 256;                                         \
                int row = idx >> 3, kq = (idx & 7) * 4;                          \
                Ws[kq + 0][row] = wr[r].x; Ws[kq + 1][row] = wr[r].y;            \
                Ws[kq + 2][row] = wr[r].z; Ws[kq + 3][row] = wr[r].w;            \
            }                                                                    \
        }

    LOADCHUNK(0);
    STASH();
    __syncthreads();

    for (int k0 = 0; k0 < K; k0 += 32) {
        bool last = (k0 + 32 >= K);
        if (!last) LOADCHUNK(k0 + 32);
        #pragma unroll
        for (int kk = 0; kk < 32; ++kk) {
            float4 a0 = *(const float4*)&Xs[kk][ty * 4];
            float4 a1 = *(const float4*)&Xs[kk][64 + ty * 4];
            float4 b0 = *(const float4*)&Ws[kk][tx * 4];
            float av[8] = {a0.x, a0.y, a0.z, a0.w, a1.x, a1.y, a1.z, a1.w};
            float bv[4] = {b0.x, b0.y, b0.z, b0.w};
            #pragma unroll
            for (int i = 0; i < 8; ++i)
                #pragma unroll
                for (int j = 0; j < 4; ++j)
                    acc[i][j] = fmaf(av[i], bv[j], acc[i][j]);
        }
        __syncthreads();
        if (!last) {
            STASH();
            __syncthreads();
        }
    }

    float4 bb = {0, 0, 0, 0};
    if (mode & 1) bb = *(const float4*)(bias + n0 + tx * 4);
    const int c0 = n0 + tx * 4;
    #pragma unroll
    for (int i = 0; i < 8; ++i) {
        int r = m0 + ((i < 4) ? (ty * 4 + i) : (64 + ty * 4 + (i - 4)));
        float v[4];
        #pragma unroll
        for (int j = 0; j < 4; ++j) {
            v[j] = acc[i][j];
            if (mode & 1) v[j] += ((const float*)&bb)[j];
        }
        if (mode & 8) {
            uchar4 mo;
            mo.x = v[0] > 0.0f; mo.y = v[1] > 0.0f; mo.z = v[2] > 0.0f; mo.w = v[3] > 0.0f;
            *(uchar4*)&maskOut[(size_t)r * N + c0] = mo;
        }
        if (mode & 16) {
            uchar4 mm = *(const uchar4*)&maskMul[(size_t)r * N + c0];
            v[0] *= mm.x; v[1] *= mm.y; v[2] *= mm.z; v[3] *= mm.w;
        }
        if (mode & 2) {
            #pragma unroll
            for (int j = 0; j < 4; ++j) v[j] = fmaxf(v[j], 0.0f);
        }
        if (mode & 4) {
            float4 st = {v[0], v[1], v[2], v[3]};
            *(float4*)(C + (size_t)r * ldc + c0) = st;
        }
    }
}

// ======== split-bf16 MFMA GEMM (R9-validated) — V1,V2,V3 ========
__global__ __launch_bounds__(128) void gemm3(
    const float* __restrict__ X, int ldx,
    const unsigned short* __restrict__ Whi, const unsigned short* __restrict__ Wlo, int ldw,
    float* __restrict__ C, int ldc,
    const unsigned char* __restrict__ maskMul,
    int K, int N, int mode)
{
    __shared__ __align__(16) unsigned short Xh[128 * 40];
    __shared__ __align__(16) unsigned short Xl[128 * 40];
    __shared__ __align__(16) unsigned short Wsh[64 * 40];
    __shared__ __align__(16) unsigned short Wsl[64 * 40];

    const int tid = threadIdx.x;
    const int m0 = blockIdx.x * 128;
    const int n0 = blockIdx.y * 64;
    const int wave = tid >> 6, lane = tid & 63;
    const int q = lane >> 4, ln = lane & 15;

    f4v acc[4][4];
    #pragma unroll
    for (int mt = 0; mt < 4; ++mt)
        #pragma unroll
        for (int nt = 0; nt < 4; ++nt)
            acc[mt][nt] = (f4v)(0.0f);

    float4 xr[8];
    s8v wh[2], wl[2];

    #define LOADC3(k0)                                                             \
        {                                                                          \
            _Pragma("unroll")                                                      \
            for (int r = 0; r < 8; ++r) {                                          \
                int idx = tid + r * 128;                                           \
                int row = idx >> 3, kq = (idx & 7) * 4;                            \
                xr[r] = *(const float4*)(X + (size_t)(m0 + row) * ldx + (k0) + kq); \
            }                                                                      \
            _Pragma("unroll")                                                      \
            for (int r = 0; r < 2; ++r) {                                          \
                int idx = tid + r * 128;                                           \
                int row = idx >> 2, kc = (idx & 3) * 8;                            \
                wh[r] = *(const s8v*)(Whi + (size_t)(n0 + row) * ldw + (k0) + kc); \
                wl[r] = *(const s8v*)(Wlo + (size_t)(n0 + row) * ldw + (k0) + kc); \
            }                                                                      \
        }
    #define STASH3()                                                               \
        {                                                                          \
            _Pragma("unroll")                                                      \
            for (int r = 0; r < 8; ++r) {                                          \
                int idx = tid + r * 128;                                           \
                int row = idx >> 3, kq = (idx & 7) * 4;                            \
                float a[4] = {xr[r].x, xr[r].y, xr[r].z, xr[r].w};                 \
                s4v hv, lv;                                                        \
                _Pragma("unroll")                                                  \
                for (int j = 0; j < 4; ++j) {                                      \
                    unsigned short h = f2bf(a[j]);                                 \
                    hv[j] = (short)h;                                              \
                    lv[j] = (short)f2bf(a[j] - bf2f(h));                           \
                }                                                                  \
                *(s4v*)&Xh[row * 40 + kq] = hv;                                    \
                *(s4v*)&Xl[row * 40 + kq] = lv;                                    \
            }                                                                      \
            _Pragma("unroll")                                                      \
            for (int r = 0; r < 2; ++r) {                                          \
                int idx = tid + r * 128;                                           \
                int row = idx >> 2, kc = (idx & 3) * 8;                            \
                *(s8v*)&Wsh[row * 40 + kc] = wh[r];                                \
                *(s8v*)&Wsl[row * 40 + kc] = wl[r];                                \
            }                                                                      \
        }

    LOADC3(0);
    STASH3();
    __syncthreads();

    for (int k0 = 0; k0 < K; k0 += 32) {
        bool last = (k0 + 32 >= K);
        if (!last) LOADC3(k0 + 32);

        s8v ah[4], al[4], bh[4], bl[4];
        #pragma unroll
        for (int mt = 0; mt < 4; ++mt) {
            int rowm = wave * 64 + mt * 16 + ln;
            ah[mt] = *(const s8v*)&Xh[rowm * 40 + q * 8];
            al[mt] = *(const s8v*)&Xl[rowm * 40 + q * 8];
        }
        #pragma unroll
        for (int nt = 0; nt < 4; ++nt) {
            int rown = nt * 16 + ln;
            bh[nt] = *(const s8v*)&Wsh[rown * 40 + q * 8];
            bl[nt] = *(const s8v*)&Wsl[rown * 40 + q * 8];
        }
        #pragma unroll
        for (int mt = 0; mt < 4; ++mt)
            #pragma unroll
            for (int nt = 0; nt < 4; ++nt) {
                acc[mt][nt] = __builtin_amdgcn_mfma_f32_16x16x32_bf16(ah[mt], bh[nt], acc[mt][nt], 0, 0, 0);
                acc[mt][nt] = __builtin_amdgcn_mfma_f32_16x16x32_bf16(ah[mt], bl[nt], acc[mt][nt], 0, 0, 0);
                acc[mt][nt] = __builtin_amdgcn_mfma_f32_16x16x32_bf16(al[mt], bh[nt], acc[mt][nt], 0, 0, 0);
            }

        __syncthreads();
        if (!last) {
            STASH3();
            __syncthreads();
        }
    }

    #pragma unroll
    for (int nt = 0; nt < 4; ++nt) {
        int n = n0 + nt * 16 + ln;
        #pragma unroll
        for (int mt = 0; mt < 4; ++mt) {
            int mbase = m0 + wave * 64 + mt * 16 + q * 4;
            #pragma unroll
            for (int r = 0; r < 4; ++r) {
                int m = mbase + r;
                float v = acc[mt][nt][r];
                if (mode & 16) v *= (float)maskMul[(size_t)m * N + n];
                if (mode & 2)  v = fmaxf(v, 0.0f);
                if (mode & 4)  C[(size_t)m * ldc + n] = v;
            }
        }
    }
}

// ---------- zng: bf16 MFMA Jacobian chain ----------
// R14: 1 elem/block, 32x32x16 MFMA, LDS 66.5 KB -> 2 blocks/CU (anti-phased
// independent blocks cover each other's epilogue/barrier stalls).
// __launch_bounds__(512,4) caps combined VGPR+AGPR at 128 for 4 waves/SIMD.
// Swizzle: logical 8-short chunk c of row rn stored at slot c^(rn&7)
// (identical convention to R10/R13; read/write patterns re-verified bank-balanced).
// Fragment layouts (HW-verified, m74/m101): A/B row=lane&31, k=(lane>>5)*8+j;
// C col=lane&31, row=(reg&3)+8*(reg>>2)+4*(lane>>5).
__global__ __launch_bounds__(512, 4) void zng_kernel(
    const unsigned short* __restrict__ whbf,   // [2][512][512] bf16 (layers 1,2)
    const unsigned short* __restrict__ woutbf, // [64][512] bf16
    const unsigned short* __restrict__ G0tb,   // [64][512] bf16 (G0 transposed)
    const unsigned char* __restrict__ mz1,
    const unsigned char* __restrict__ mz2,
    const unsigned char* __restrict__ mz3,
    float* __restrict__ out)                   // (4096,192), writes cols 128..191
{
    __shared__ __align__(16) unsigned short Rt[64 * 512]; // 65536 B, swizzled
    __shared__ unsigned char m2s[512];
    __shared__ unsigned char m3s[512];

    const int b0  = blockIdx.x;     // one batch element per block
    const int tid = threadIdx.x;

    m2s[tid] = mz2[(size_t)b0 * 512 + tid];
    m3s[tid] = mz3[(size_t)b0 * 512 + tid];

    // ---- setup: Rt = (mask1 (.) G0)^T, swizzled ----
    #pragma unroll
    for (int i = 0; i < 8; ++i) {
        int c = i * 512 + tid;             // 0..4095
        int n = c >> 6, ch = c & 63;
        int k = ch * 8;
        s8v g = *(const s8v*)(G0tb + n * 512 + k);
        const unsigned char* mm = mz1 + (size_t)b0 * 512 + k;
        unsigned int mlo = *(const unsigned int*)(mm);
        unsigned int mhi = *(const unsigned int*)(mm + 4);
        s8v r;
        #pragma unroll
        for (int j = 0; j < 4; ++j) r[j] = ((mlo >> (8 * j)) & 1) ? g[j] : (short)0;
        #pragma unroll
        for (int j = 0; j < 4; ++j) r[4 + j] = ((mhi >> (8 * j)) & 1) ? g[4 + j] : (short)0;
        *(s8v*)(&Rt[n * 512 + ((ch ^ (n & 7)) << 3)]) = r;
    }
    __syncthreads();

    const int lane = tid & 63, wave = tid >> 6;
    const int l31 = lane & 31, h = lane >> 5;
    const int l7 = l31 & 7;

    // ---- 2 chained layers: R <- mask (.) (Wh @ R) ----
    for (int s = 0; s < 2; ++s) {
        const unsigned short* Ar0 = whbf + (size_t)s * 262144
                                  + (size_t)(wave * 64 + l31) * 512 + h * 8;
        const unsigned short* Ar1 = Ar0 + 32 * 512;

        f16v acc[2][2];
        #pragma unroll
        for (int mt = 0; mt < 2; ++mt)
            #pragma unroll
            for (int nt = 0; nt < 2; ++nt)
                acc[mt][nt] = (f16v)(0.0f);

        // 1-deep prefetch of A (global/L2) and B (LDS)
        s8v a0c = *(const s8v*)(Ar0);
        s8v a1c = *(const s8v*)(Ar1);
        int cc0 = ((h ^ l7) << 3);
        s8v b0c = *(const s8v*)&Rt[l31 * 512 + cc0];
        s8v b1c = *(const s8v*)&Rt[(32 + l31) * 512 + cc0];

        #pragma unroll 2
        for (int ks = 0; ks < 32; ++ks) {
            int kn = ((ks + 1) & 31) * 16;            // wraps; redundant tail loads
            s8v a0n = *(const s8v*)(Ar0 + kn);
            s8v a1n = *(const s8v*)(Ar1 + kn);
            int cn = (((((ks + 1) & 31) * 2 + h) ^ l7) << 3);
            s8v b0n = *(const s8v*)&Rt[l31 * 512 + cn];
            s8v b1n = *(const s8v*)&Rt[(32 + l31) * 512 + cn];

            __builtin_amdgcn_s_setprio(1);
            acc[0][0] = __builtin_amdgcn_mfma_f32_32x32x16_bf16(a0c, b0c, acc[0][0], 0, 0, 0);
            acc[0][1] = __builtin_amdgcn_mfma_f32_32x32x16_bf16(a0c, b1c, acc[0][1], 0, 0, 0);
            acc[1][0] = __builtin_amdgcn_mfma_f32_32x32x16_bf16(a1c, b0c, acc[1][0], 0, 0, 0);
            acc[1][1] = __builtin_amdgcn_mfma_f32_32x32x16_bf16(a1c, b1c, acc[1][1], 0, 0, 0);
            __builtin_amdgcn_s_setprio(0);

            a0c = a0n; a1c = a1n; b0c = b0n; b1c = b1n;
        }
        __syncthreads();

        // ---- epilogue: mask, pack bf16, write new R^T (swizzled) ----
        const unsigned char* msk = (s == 0) ? m2s : m3s;
        #pragma unroll
        for (int mt = 0; mt < 2; ++mt) {
            #pragma unroll
            for (int g = 0; g < 4; ++g) {
                int mbase = wave * 64 + mt * 32 + g * 8 + h * 4;  // output row group
                int cw = wave * 8 + mt * 4 + g;                   // chunk = mbase>>3
                uchar4 mv = *(const uchar4*)&msk[mbase];
                unsigned char mb[4] = {mv.x, mv.y, mv.z, mv.w};
                #pragma unroll
                for (int nt = 0; nt < 2; ++nt) {
                    int rn = nt * 32 + l31;
                    s4v pk;
                    #pragma unroll
                    for (int r = 0; r < 4; ++r) {
                        float v = mb[r] ? acc[mt][nt][g * 4 + r] : 0.0f;
                        pk[r] = (short)f2bf(v);
                    }
                    *(s4v*)(&Rt[rn * 512 + ((cw ^ (rn & 7)) << 3) + h * 4]) = pk;
                }
            }
        }
        __syncthreads();
    }

    // ---- final: Wout @ R, row norms; waves 0-1 only (no barriers below) ----
    if (wave < 2) {
        const unsigned short* Wr = woutbf + (size_t)(wave * 32 + l31) * 512 + h * 8;
        f16v a3[2];
        a3[0] = (f16v)(0.0f);
        a3[1] = (f16v)(0.0f);
        for (int ks = 0; ks < 32; ++ks) {
            s8v af = *(const s8v*)(Wr + ks * 16);
            int cc = (((ks * 2 + h) ^ l7) << 3);
            s8v bb0 = *(const s8v*)&Rt[l31 * 512 + cc];
            s8v bb1 = *(const s8v*)&Rt[(32 + l31) * 512 + cc];
            a3[0] = __builtin_amdgcn_mfma_f32_32x32x16_bf16(af, bb0, a3[0], 0, 0, 0);
            a3[1] = __builtin_amdgcn_mfma_f32_32x32x16_bf16(af, bb1, a3[1], 0, 0, 0);
        }
        // per-lane: rows wave*32 + g*8 + h*4 + r, cols (nt*32 + l31)
        float sq[16];
        #pragma unroll
        for (int i = 0; i < 16; ++i) {
            float v0 = a3[0][i], v1 = a3[1][i];
            sq[i] = fmaf(v0, v0, v1 * v1);
        }
        #pragma unroll
        for (int off = 1; off < 32; off <<= 1)
            #pragma unroll
            for (int i = 0; i < 16; ++i)
                sq[i] += __shfl_xor(sq[i], off, 64);
        if (l31 == 0) {
            #pragma unroll
            for (int g = 0; g < 4; ++g)
                #pragma unroll
                for (int r = 0; r < 4; ++r)
                    out[(size_t)b0 * 192 + 128 + wave * 32 + g * 8 + h * 4 + r] = sqrtf(sq[g * 4 + r]);
        }
    }
}

// ---------- host ----------
extern "C" void kernel_launch(void* const* d_in, const int* in_sizes, int n_in,
                              void* d_out, int out_size, void* d_ws, size_t ws_size,
                              hipStream_t stream) {
    const float* x    = (const float*)d_in[0];
    const float* Win  = (const float*)d_in[1];
    const float* bin  = (const float*)d_in[2];
    const float* Wh   = (const float*)d_in[3];
    const float* bh   = (const float*)d_in[4];
    const float* Wout = (const float*)d_in[5];
    const float* bout = (const float*)d_in[6];
    float* out = (float*)d_out;

    char* ws = (char*)d_ws;
    unsigned short* whi  = (unsigned short*)(ws);                   // 1703936 B
    unsigned short* wlo  = (unsigned short*)(ws + 1703936);         // 1703936 B
    unsigned short* G0hi = (unsigned short*)(ws + 3407872);         // 65536 B
    unsigned short* G0lo = (unsigned short*)(ws + 3473408);         // 65536 B
    unsigned short* G0tb = (unsigned short*)(ws + 3538944);         // 65536 B
    unsigned char*  masks = (unsigned char*)(ws + 3604480);         // 6 * 2 MB
    unsigned char* mt1 = masks + 0 * 2097152;
    unsigned char* mt2 = masks + 1 * 2097152;
    unsigned char* mt3 = masks + 2 * 2097152;
    unsigned char* mz1 = masks + 3 * 2097152;
    unsigned char* mz2 = masks + 4 * 2097152;
    unsigned char* mz3 = masks + 5 * 2097152;
    float* bufs = (float*)(ws + 3604480 + 12582912);                // 4 x 8 MB
    float* tA = bufs + 0 * 2097152;
    float* tB = bufs + 1 * 2097152;
    float* zA = bufs + 2 * 2097152;
    float* zB = bufs + 3 * 2097152;

    // hi/lo plane offsets (elems): [Win@0 | Wh0@32768 | Wh1@294912 | Wh2@557056 | Wout@819200]
    const unsigned short* WinH  = whi,          *WinL  = wlo;
    const unsigned short* Wh0H  = whi + 32768,  *Wh0L  = wlo + 32768;
    const unsigned short* Wh1H  = whi + 294912, *Wh1L  = wlo + 294912;
    const unsigned short* Wh2H  = whi + 557056, *Wh2L  = wlo + 557056;
    const unsigned short* WoutH = whi + 819200;

    const float* Wh0 = Wh;
    const float* Wh1 = Wh + 262144;
    const float* Wh2 = Wh + 524288;
    const float* bh0 = bh, *bh1 = bh + 512, *bh2 = bh + 1024;

    conv_split<<<dim3(3328), dim3(256), 0, stream>>>(Win, Wh, Wout, whi, wlo);
    g0_kernel<<<dim3(512), dim3(64), 0, stream>>>(Wh0, Win, G0hi, G0lo, G0tb);

    auto gdual = [&](const float* X0, const float* X1, int ldx,
                     const float* W, const unsigned short* WH, const unsigned short* WL, int ldw,
                     const float* bias, float* C0, float* C1, int ldc,
                     unsigned char* mo0, unsigned char* mo1,
                     const unsigned char* mm0, const unsigned char* mm1,
                     int K, int N, int mode) {
        dim3 g(4096 / 128, N / 64, 2);
        gemm_dual<<<g, dim3(512), 0, stream>>>(X0, X1, ldx, W, ldw, WH, WL, bias,
                                               C0, C1, ldc, mo0, mo1, mm0, mm1, K, N, mode);
    };
    auto gemm1 = [&](const float* X, int ldx, const float* W, int ldw, const float* bias,
                     float* C, int ldc, unsigned char* mo, const unsigned char* mm,
                     int K, int N, int mode) {
        dim3 g(4096 / 128, N / 64, 1);
        gemm_nt<<<g, dim3(256), 0, stream>>>(X, ldx, W, ldw, bias, C, ldc, mo, mm, K, N, mode);
    };
    auto g3 = [&](const float* X, int ldx,
                  const unsigned short* WH, const unsigned short* WL, int ldw,
                  float* C, int ldc, const unsigned char* mm, int K, int N, int mode) {
        dim3 g(4096 / 128, N / 64, 1);
        gemm3<<<g, dim3(128), 0, stream>>>(X, ldx, WH, WL, ldw, C, ldc, mm, K, N, mode);
    };

    // ---- fused forward + delta chain (t fp32 ; z split-bf16 MFMA) ----
    gdual(x, x + 128, 192, Win, WinH, WinL, 64, bin, tA, zA, 512, 0, 0, 0, 0, 64, 512, 1 | 4);        // h0
    gdual(tA, zA, 512, Wh0, Wh0H, Wh0L, 512, bh0,   tB, zB, 512, 0, 0, 0, 0, 512, 512, 1 | 2 | 4);    // h1
    gdual(tB, zB, 512, Wh0, Wh0H, Wh0L, 512, bh0,   0, 0, 0, mt1, mz1, 0, 0, 512, 512, 1 | 8);        // delta1
    gdual(tB, zB, 512, Wh1, Wh1H, Wh1L, 512, bh1,   tA, zA, 512, 0, 0, 0, 0, 512, 512, 1 | 2 | 4);    // h2
    gdual(tA, zA, 512, Wh1, Wh1H, Wh1L, 512, bh1,   0, 0, 0, mt2, mz2, 0, 0, 512, 512, 1 | 8);        // delta2
    gdual(tA, zA, 512, Wh2, Wh2H, Wh2L, 512, bh2,   tB, zB, 512, 0, 0, 0, 0, 512, 512, 1 | 2 | 4);    // h3
    gdual(tB, zB, 512, Wh2, Wh2H, Wh2L, 512, bh2,   0, 0, 0, mt3, mz3, 0, 0, 512, 512, 1 | 8);        // delta3

    // ---- zng (z-branch Jacobian row norms), 1 elem/block, 2 blocks/CU ----
    zng_kernel<<<dim3(4096), dim3(512), 0, stream>>>(Wh1H, WoutH, G0tb, mz1, mz2, mz3, out);

    // ---- h_out (t-branch forward output) — fp32 ----
    gemm1(tB, 512, Wout, 512, bout, out, 192, 0, 0, 512, 64, 1 | 4);                                  // cols 0..63

    // ---- h_dot chain: V = D (.) (W v) ----
    g3(x + 64, 192, G0hi, G0lo, 64, tA, 512, mt1, 64, 512, 4 | 16);                                   // V1 (split-bf16)
    g3(tA, 512, Wh1H, Wh1L, 512, zA, 512, mt2, 512, 512, 4 | 16);                                     // V2 (split-bf16)
    g3(zA, 512, Wh2H, Wh2L, 512, zB, 512, mt3, 512, 512, 4 | 16);                                     // V3 (split-bf16)
    gemm1(zB, 512, Wout, 512, 0, out + 64, 192, 0, 0, 512, 64, 4);                                    // h_dot (fp32)
}

// Round 2
// 801.035 us; speedup vs baseline: 1.2647x; 1.2647x over previous
//
#include <hip/hip_runtime.h>
#include <math.h>

typedef __attribute__((ext_vector_type(8))) short s8v;   // 8 x bf16
typedef __attribute__((ext_vector_type(4))) short s4v;   // 4 x bf16
typedef __attribute__((ext_vector_type(4))) float f4v;   // 4 x f32
typedef __attribute__((ext_vector_type(16))) float f16v; // 16 x f32

static __device__ __forceinline__ unsigned short f2bf(float f) {
    union { float f; unsigned int u; } v; v.f = f;
    unsigned int r = v.u + 0x7fffu + ((v.u >> 16) & 1u);   // RNE
    return (unsigned short)(r >> 16);
}
static __device__ __forceinline__ float bf2f(unsigned short h) {
    union { unsigned int u; float f; } t; t.u = ((unsigned int)h) << 16;
    return t.f;
}

// ---------- split all weights to bf16 hi/lo planes ----------
// layout: [Win(32768) | Wh0 | Wh1 | Wh2 (262144 each) | Wout(32768)] = 851968
__global__ void conv_split(const float* __restrict__ Win, const float* __restrict__ Wh,
                           const float* __restrict__ Wout,
                           unsigned short* __restrict__ whi, unsigned short* __restrict__ wlo) {
    int i = blockIdx.x * 256 + threadIdx.x;
    if (i >= 851968) return;
    float v;
    if (i < 32768)       v = Win[i];
    else if (i < 819200) v = Wh[i - 32768];
    else                 v = Wout[i - 819200];
    unsigned short h = f2bf(v);
    whi[i] = h;
    wlo[i] = f2bf(v - bf2f(h));
}

// ---------- pack zng weights into MFMA-fragment order (coalesced A-loads) ----------
// WhF[layer s][g32][ks][lane]: s8v = Wh_{1+s}[g32*32+(lane&31)][ks*16+(lane>>5)*8 .. +7]
// WoF[g32][ks][lane]:          s8v = Wout  [g32*32+(lane&31)][ks*16+(lane>>5)*8 .. +7]
// A wave reading lanes 0..63 at frag index f gets 1KB contiguous.
__global__ void frag_pack(const unsigned short* __restrict__ whi,
                          unsigned short* __restrict__ WhF,   // [2][16][32][64][8] = 1 MB
                          unsigned short* __restrict__ WoF) { // [2][32][64][8] = 64 KB
    int i = blockIdx.x * 256 + threadIdx.x;     // fragment-slot (s8v) index
    if (i < 65536) {
        int lane = i & 63, ks = (i >> 6) & 31, g32 = (i >> 11) & 15, s = i >> 15;
        int row = g32 * 32 + (lane & 31);
        int k   = ks * 16 + (lane >> 5) * 8;
        const unsigned short* src = whi + 294912 + (size_t)s * 262144 + row * 512 + k;
        *(s8v*)(WhF + (size_t)i * 8) = *(const s8v*)src;
    } else if (i < 65536 + 4096) {
        int j = i - 65536;
        int lane = j & 63, ks = (j >> 6) & 31, g32 = j >> 11;
        int row = g32 * 32 + (lane & 31);
        int k   = ks * 16 + (lane >> 5) * 8;
        const unsigned short* src = whi + 819200 + row * 512 + k;
        *(s8v*)(WoF + (size_t)j * 8) = *(const s8v*)src;
    }
}

// ---------- G0 = Wh0 @ W_in (512x64): hi/lo planes + transposed hi for zng ----------
__global__ void g0_kernel(const float* __restrict__ Wh0, const float* __restrict__ Win,
                          unsigned short* __restrict__ G0hi, unsigned short* __restrict__ G0lo,
                          unsigned short* __restrict__ G0tb) {
    int i = blockIdx.x;      // 0..511
    int j = threadIdx.x;     // 0..63
    float acc = 0.f;
    for (int k = 0; k < 512; ++k)
        acc = fmaf(Wh0[i * 512 + k], Win[k * 64 + j], acc);
    unsigned short h = f2bf(acc);
    G0hi[i * 64 + j] = h;
    G0lo[i * 64 + j] = f2bf(acc - bf2f(h));
    G0tb[j * 512 + i] = h;
}

// ======== dual GEMM, 512 threads (R13-validated): z=0 fp32 4x4 micro (t branch);
//          z=1 split-bf16 MFMA, 8 waves of 32x32 (z branch, flip-tolerant).
__global__ __launch_bounds__(512) void gemm_dual(
    const float* __restrict__ X0, const float* __restrict__ X1, int ldx,
    const float* __restrict__ W, int ldw,
    const unsigned short* __restrict__ Whi, const unsigned short* __restrict__ Wlo,
    const float* __restrict__ bias,
    float* __restrict__ C0, float* __restrict__ C1, int ldc,
    unsigned char* __restrict__ mo0, unsigned char* __restrict__ mo1,
    const unsigned char* __restrict__ mm0, const unsigned char* __restrict__ mm1,
    int K, int N, int mode)
{
    __shared__ __align__(16) unsigned char lds[30720];
    const int tid = threadIdx.x;
    const int m0 = blockIdx.x * 128;
    const int n0 = blockIdx.y * 64;

    if (blockIdx.z == 0) {
        // ---------------- fp32 vector path, 4x4 micro ----------------
        const float* __restrict__ X = X0;
        float* __restrict__ C = C0;
        unsigned char* __restrict__ maskOut = mo0;
        const unsigned char* __restrict__ maskMul = mm0;
        float (*Xs)[132] = (float(*)[132])lds;                 // 16896 B
        float (*Ws)[68]  = (float(*)[68])(lds + 16896);        // 8704 B
        const int tx = tid & 15, ty = tid >> 4;                // ty 0..31
        float acc[4][4] = {};
        float4 xr[2], wr;

        #define LOADF(k0)                                                            \
            {                                                                        \
                _Pragma("unroll")                                                    \
                for (int r = 0; r < 2; ++r) {                                        \
                    int idx = tid + r * 512;                                         \
                    int row = idx >> 3, kq = (idx & 7) * 4;                          \
                    xr[r] = *(const float4*)(X + (size_t)(m0 + row) * ldx + (k0) + kq); \
                }                                                                    \
                {                                                                    \
                    int row = tid >> 3, kq = (tid & 7) * 4;                          \
                    wr = *(const float4*)(W + (size_t)(n0 + row) * ldw + (k0) + kq); \
                }                                                                    \
            }
        #define STASHF()                                                             \
            {                                                                        \
                _Pragma("unroll")                                                    \
                for (int r = 0; r < 2; ++r) {                                        \
                    int idx = tid + r * 512;                                         \
                    int row = idx >> 3, kq = (idx & 7) * 4;                          \
                    Xs[kq + 0][row] = xr[r].x; Xs[kq + 1][row] = xr[r].y;            \
                    Xs[kq + 2][row] = xr[r].z; Xs[kq + 3][row] = xr[r].w;            \
                }                                                                    \
                {                                                                    \
                    int row = tid >> 3, kq = (tid & 7) * 4;                          \
                    Ws[kq + 0][row] = wr.x; Ws[kq + 1][row] = wr.y;                  \
                    Ws[kq + 2][row] = wr.z; Ws[kq + 3][row] = wr.w;                  \
                }                                                                    \
            }

        LOADF(0);
        STASHF();
        __syncthreads();

        for (int k0 = 0; k0 < K; k0 += 32) {
            bool last = (k0 + 32 >= K);
            if (!last) LOADF(k0 + 32);
            #pragma unroll
            for (int kk = 0; kk < 32; ++kk) {
                float4 a0 = *(const float4*)&Xs[kk][ty * 4];
                float4 b0 = *(const float4*)&Ws[kk][tx * 4];
                float av[4] = {a0.x, a0.y, a0.z, a0.w};
                float bv[4] = {b0.x, b0.y, b0.z, b0.w};
                #pragma unroll
                for (int i = 0; i < 4; ++i)
                    #pragma unroll
                    for (int j = 0; j < 4; ++j)
                        acc[i][j] = fmaf(av[i], bv[j], acc[i][j]);
            }
            __syncthreads();
            if (!last) {
                STASHF();
                __syncthreads();
            }
        }

        float4 bb = {0, 0, 0, 0};
        if (mode & 1) bb = *(const float4*)(bias + n0 + tx * 4);
        const int c0 = n0 + tx * 4;
        #pragma unroll
        for (int i = 0; i < 4; ++i) {
            int r = m0 + ty * 4 + i;
            float v[4];
            #pragma unroll
            for (int j = 0; j < 4; ++j) {
                v[j] = acc[i][j];
                if (mode & 1) v[j] += ((const float*)&bb)[j];
            }
            if (mode & 8) {
                uchar4 mo;
                mo.x = v[0] > 0.0f; mo.y = v[1] > 0.0f; mo.z = v[2] > 0.0f; mo.w = v[3] > 0.0f;
                *(uchar4*)&maskOut[(size_t)r * N + c0] = mo;
            }
            if (mode & 16) {
                uchar4 mm = *(const uchar4*)&maskMul[(size_t)r * N + c0];
                v[0] *= mm.x; v[1] *= mm.y; v[2] *= mm.z; v[3] *= mm.w;
            }
            if (mode & 2) {
                #pragma unroll
                for (int j = 0; j < 4; ++j) v[j] = fmaxf(v[j], 0.0f);
            }
            if (mode & 4) {
                float4 st = {v[0], v[1], v[2], v[3]};
                *(float4*)(C + (size_t)r * ldc + c0) = st;
            }
        }
    } else {
        // ---------------- split-bf16 MFMA path, 8 waves of 32x32 ----------------
        const float* __restrict__ X = X1;
        float* __restrict__ C = C1;
        unsigned char* __restrict__ maskOut = mo1;
        const unsigned char* __restrict__ maskMul = mm1;
        unsigned short* Xh  = (unsigned short*)lds;            // 128*40 = 10240 B
        unsigned short* Xl  = (unsigned short*)(lds + 10240);  // 10240 B
        unsigned short* Wsh = (unsigned short*)(lds + 20480);  // 5120 B
        unsigned short* Wsl = (unsigned short*)(lds + 25600);  // 5120 B

        const int wave = tid >> 6, lane = tid & 63;
        const int q = lane >> 4, ln = lane & 15;
        const int wm = (wave & 3) * 32;      // m-offset (0..96)
        const int wn = (wave >> 2) * 32;     // n-offset (0/32)

        f4v acc[2][2];
        #pragma unroll
        for (int mt = 0; mt < 2; ++mt)
            #pragma unroll
            for (int nt = 0; nt < 2; ++nt)
                acc[mt][nt] = (f4v)(0.0f);

        float4 xr[2];
        s8v wh, wl;
        const bool wload = (tid < 256);

        #define LOADD(k0)                                                              \
            {                                                                          \
                _Pragma("unroll")                                                      \
                for (int r = 0; r < 2; ++r) {                                          \
                    int idx = tid + r * 512;                                           \
                    int row = idx >> 3, kq = (idx & 7) * 4;                            \
                    xr[r] = *(const float4*)(X + (size_t)(m0 + row) * ldx + (k0) + kq); \
                }                                                                      \
                if (wload) {                                                           \
                    int row = tid >> 2, kc = (tid & 3) * 8;                            \
                    wh = *(const s8v*)(Whi + (size_t)(n0 + row) * ldw + (k0) + kc);    \
                    wl = *(const s8v*)(Wlo + (size_t)(n0 + row) * ldw + (k0) + kc);    \
                }                                                                      \
            }
        #define STASHD()                                                               \
            {                                                                          \
                _Pragma("unroll")                                                      \
                for (int r = 0; r < 2; ++r) {                                          \
                    int idx = tid + r * 512;                                           \
                    int row = idx >> 3, kq = (idx & 7) * 4;                            \
                    float a[4] = {xr[r].x, xr[r].y, xr[r].z, xr[r].w};                 \
                    s4v hv, lv;                                                        \
                    _Pragma("unroll")                                                  \
                    for (int j = 0; j < 4; ++j) {                                      \
                        unsigned short h = f2bf(a[j]);                                 \
                        hv[j] = (short)h;                                              \
                        lv[j] = (short)f2bf(a[j] - bf2f(h));                           \
                    }                                                                  \
                    *(s4v*)&Xh[row * 40 + kq] = hv;                                    \
                    *(s4v*)&Xl[row * 40 + kq] = lv;                                    \
                }                                                                      \
                if (wload) {                                                           \
                    int row = tid >> 2, kc = (tid & 3) * 8;                            \
                    *(s8v*)&Wsh[row * 40 + kc] = wh;                                   \
                    *(s8v*)&Wsl[row * 40 + kc] = wl;                                   \
                }                                                                      \
            }

        LOADD(0);
        STASHD();
        __syncthreads();

        for (int k0 = 0; k0 < K; k0 += 32) {
            bool last = (k0 + 32 >= K);
            if (!last) LOADD(k0 + 32);

            s8v ah[2], al[2], bh[2], bl[2];
            #pragma unroll
            for (int mt = 0; mt < 2; ++mt) {
                int rowm = wm + mt * 16 + ln;
                ah[mt] = *(const s8v*)&Xh[rowm * 40 + q * 8];
                al[mt] = *(const s8v*)&Xl[rowm * 40 + q * 8];
            }
            #pragma unroll
            for (int nt = 0; nt < 2; ++nt) {
                int rown = wn + nt * 16 + ln;
                bh[nt] = *(const s8v*)&Wsh[rown * 40 + q * 8];
                bl[nt] = *(const s8v*)&Wsl[rown * 40 + q * 8];
            }
            #pragma unroll
            for (int mt = 0; mt < 2; ++mt)
                #pragma unroll
                for (int nt = 0; nt < 2; ++nt) {
                    acc[mt][nt] = __builtin_amdgcn_mfma_f32_16x16x32_bf16(ah[mt], bh[nt], acc[mt][nt], 0, 0, 0);
                    acc[mt][nt] = __builtin_amdgcn_mfma_f32_16x16x32_bf16(ah[mt], bl[nt], acc[mt][nt], 0, 0, 0);
                    acc[mt][nt] = __builtin_amdgcn_mfma_f32_16x16x32_bf16(al[mt], bh[nt], acc[mt][nt], 0, 0, 0);
                }

            __syncthreads();
            if (!last) {
                STASHD();
                __syncthreads();
            }
        }

        // epilogue: C-layout col=lane&15, row=q*4+r (m89-verified)
        #pragma unroll
        for (int nt = 0; nt < 2; ++nt) {
            int n = n0 + wn + nt * 16 + ln;
            float bv = (mode & 1) ? bias[n] : 0.0f;
            #pragma unroll
            for (int mt = 0; mt < 2; ++mt) {
                int mbase = m0 + wm + mt * 16 + q * 4;
                #pragma unroll
                for (int r = 0; r < 4; ++r) {
                    int m = mbase + r;
                    float v = acc[mt][nt][r] + bv;
                    if (mode & 8)  maskOut[(size_t)m * N + n] = (v > 0.0f) ? 1 : 0;
                    if (mode & 16) v *= (float)maskMul[(size_t)m * N + n];
                    if (mode & 2)  v = fmaxf(v, 0.0f);
                    if (mode & 4)  C[(size_t)m * ldc + n] = v;
                }
            }
        }
    }
}

// ======== fp32 GEMM 128x64 (R4-validated) — t-branch finals ========
__global__ __launch_bounds__(256) void gemm_nt(
    const float* __restrict__ X, int ldx,
    const float* __restrict__ W, int ldw,
    const float* __restrict__ bias,
    float* __restrict__ C, int ldc,
    unsigned char* __restrict__ maskOut,
    const unsigned char* __restrict__ maskMul,
    int K, int N, int mode)
{
    __shared__ float Xs[32][132];
    __shared__ float Ws[32][68];
    const int tid = threadIdx.x;
    const int m0 = blockIdx.x * 128;
    const int n0 = blockIdx.y * 64;
    const int tx = tid & 15, ty = tid >> 4;
    float acc[8][4] = {};
    float4 xr[4], wr[2];

    #define LOADCHUNK(k0)                                                        \
        {                                                                        \
            _Pragma("unroll")                                                    \
            for (int r = 0; r < 4; ++r) {                                        \
                int idx = tid + r * 256;                                         \
                int row = idx >> 3, kq = (idx & 7) * 4;                          \
                xr[r] = *(const float4*)(X + (size_t)(m0 + row) * ldx + (k0) + kq); \
            }                                                                    \
            _Pragma("unroll")                                                    \
            for (int r = 0; r < 2; ++r) {                                        \
                int idx = tid + r * 256;                                         \
                int row = idx >> 3, kq = (idx & 7) * 4;                          \
                wr[r] = *(const float4*)(W + (size_t)(n0 + row) * ldw + (k0) + kq); \
            }                                                                    \
        }
    #define STASH()                                                              \
        {                                                                        \
            _Pragma("unroll")                                                    \
            for (int r = 0; r < 4; ++r) {                                        \
                int idx = tid + r * 256;                                         \
                int row = idx >> 3, kq = (idx & 7) * 4;                          \
                Xs[kq + 0][row] = xr[r].x; Xs[kq + 1][row] = xr[r].y;            \
                Xs[kq + 2][row] = xr[r].z; Xs[kq + 3][row] = xr[r].w;            \
            }                                                                    \
            _Pragma("unroll")                                                    \
            for (int r = 0; r < 2; ++r) {                                        \
                int idx = tid + r * 256;                                         \
                int row = idx >> 3, kq = (idx & 7) * 4;                          \
                Ws[kq + 0][row] = wr[r].x; Ws[kq + 1][row] = wr[r].y;            \
                Ws[kq + 2][row] = wr[r].z; Ws[kq + 3][row] = wr[r].w;            \
            }                                                                    \
        }

    LOADCHUNK(0);
    STASH();
    __syncthreads();

    for (int k0 = 0; k0 < K; k0 += 32) {
        bool last = (k0 + 32 >= K);
        if (!last) LOADCHUNK(k0 + 32);
        #pragma unroll
        for (int kk = 0; kk < 32; ++kk) {
            float4 a0 = *(const float4*)&Xs[kk][ty * 4];
            float4 a1 = *(const float4*)&Xs[kk][64 + ty * 4];
            float4 b0 = *(const float4*)&Ws[kk][tx * 4];
            float av[8] = {a0.x, a0.y, a0.z, a0.w, a1.x, a1.y, a1.z, a1.w};
            float bv[4] = {b0.x, b0.y, b0.z, b0.w};
            #pragma unroll
            for (int i = 0; i < 8; ++i)
                #pragma unroll
                for (int j = 0; j < 4; ++j)
                    acc[i][j] = fmaf(av[i], bv[j], acc[i][j]);
        }
        __syncthreads();
        if (!last) {
            STASH();
            __syncthreads();
        }
    }

    float4 bb = {0, 0, 0, 0};
    if (mode & 1) bb = *(const float4*)(bias + n0 + tx * 4);
    const int c0 = n0 + tx * 4;
    #pragma unroll
    for (int i = 0; i < 8; ++i) {
        int r = m0 + ((i < 4) ? (ty * 4 + i) : (64 + ty * 4 + (i - 4)));
        float v[4];
        #pragma unroll
        for (int j = 0; j < 4; ++j) {
            v[j] = acc[i][j];
            if (mode & 1) v[j] += ((const float*)&bb)[j];
        }
        if (mode & 8) {
            uchar4 mo;
            mo.x = v[0] > 0.0f; mo.y = v[1] > 0.0f; mo.z = v[2] > 0.0f; mo.w = v[3] > 0.0f;
            *(uchar4*)&maskOut[(size_t)r * N + c0] = mo;
        }
        if (mode & 16) {
            uchar4 mm = *(const uchar4*)&maskMul[(size_t)r * N + c0];
            v[0] *= mm.x; v[1] *= mm.y; v[2] *= mm.z; v[3] *= mm.w;
        }
        if (mode & 2) {
            #pragma unroll
            for (int j = 0; j < 4; ++j) v[j] = fmaxf(v[j], 0.0f);
        }
        if (mode & 4) {
            float4 st = {v[0], v[1], v[2], v[3]};
            *(float4*)(C + (size_t)r * ldc + c0) = st;
        }
    }
}

// ======== split-bf16 MFMA GEMM (R9-validated) — V1,V2,V3 ========
__global__ __launch_bounds__(128) void gemm3(
    const float* __restrict__ X, int ldx,
    const unsigned short* __restrict__ Whi, const unsigned short* __restrict__ Wlo, int ldw,
    float* __restrict__ C, int ldc,
    const unsigned char* __restrict__ maskMul,
    int K, int N, int mode)
{
    __shared__ __align__(16) unsigned short Xh[128 * 40];
    __shared__ __align__(16) unsigned short Xl[128 * 40];
    __shared__ __align__(16) unsigned short Wsh[64 * 40];
    __shared__ __align__(16) unsigned short Wsl[64 * 40];

    const int tid = threadIdx.x;
    const int m0 = blockIdx.x * 128;
    const int n0 = blockIdx.y * 64;
    const int wave = tid >> 6, lane = tid & 63;
    const int q = lane >> 4, ln = lane & 15;

    f4v acc[4][4];
    #pragma unroll
    for (int mt = 0; mt < 4; ++mt)
        #pragma unroll
        for (int nt = 0; nt < 4; ++nt)
            acc[mt][nt] = (f4v)(0.0f);

    float4 xr[8];
    s8v wh[2], wl[2];

    #define LOADC3(k0)                                                             \
        {                                                                          \
            _Pragma("unroll")                                                      \
            for (int r = 0; r < 8; ++r) {                                          \
                int idx = tid + r * 128;                                           \
                int row = idx >> 3, kq = (idx & 7) * 4;                            \
                xr[r] = *(const float4*)(X + (size_t)(m0 + row) * ldx + (k0) + kq); \
            }                                                                      \
            _Pragma("unroll")                                                      \
            for (int r = 0; r < 2; ++r) {                                          \
                int idx = tid + r * 128;                                           \
                int row = idx >> 2, kc = (idx & 3) * 8;                            \
                wh[r] = *(const s8v*)(Whi + (size_t)(n0 + row) * ldw + (k0) + kc); \
                wl[r] = *(const s8v*)(Wlo + (size_t)(n0 + row) * ldw + (k0) + kc); \
            }                                                                      \
        }
    #define STASH3()                                                               \
        {                                                                          \
            _Pragma("unroll")                                                      \
            for (int r = 0; r < 8; ++r) {                                          \
                int idx = tid + r * 128;                                           \
                int row = idx >> 3, kq = (idx & 7) * 4;                            \
                float a[4] = {xr[r].x, xr[r].y, xr[r].z, xr[r].w};                 \
                s4v hv, lv;                                                        \
                _Pragma("unroll")                                                  \
                for (int j = 0; j < 4; ++j) {                                      \
                    unsigned short h = f2bf(a[j]);                                 \
                    hv[j] = (short)h;                                              \
                    lv[j] = (short)f2bf(a[j] - bf2f(h));                           \
                }                                                                  \
                *(s4v*)&Xh[row * 40 + kq] = hv;                                    \
                *(s4v*)&Xl[row * 40 + kq] = lv;                                    \
            }                                                                      \
            _Pragma("unroll")                                                      \
            for (int r = 0; r < 2; ++r) {                                          \
                int idx = tid + r * 128;                                           \
                int row = idx >> 2, kc = (idx & 3) * 8;                            \
                *(s8v*)&Wsh[row * 40 + kc] = wh[r];                                \
                *(s8v*)&Wsl[row * 40 + kc] = wl[r];                                \
            }                                                                      \
        }

    LOADC3(0);
    STASH3();
    __syncthreads();

    for (int k0 = 0; k0 < K; k0 += 32) {
        bool last = (k0 + 32 >= K);
        if (!last) LOADC3(k0 + 32);

        s8v ah[4], al[4], bh[4], bl[4];
        #pragma unroll
        for (int mt = 0; mt < 4; ++mt) {
            int rowm = wave * 64 + mt * 16 + ln;
            ah[mt] = *(const s8v*)&Xh[rowm * 40 + q * 8];
            al[mt] = *(const s8v*)&Xl[rowm * 40 + q * 8];
        }
        #pragma unroll
        for (int nt = 0; nt < 4; ++nt) {
            int rown = nt * 16 + ln;
            bh[nt] = *(const s8v*)&Wsh[rown * 40 + q * 8];
            bl[nt] = *(const s8v*)&Wsl[rown * 40 + q * 8];
        }
        #pragma unroll
        for (int mt = 0; mt < 4; ++mt)
            #pragma unroll
            for (int nt = 0; nt < 4; ++nt) {
                acc[mt][nt] = __builtin_amdgcn_mfma_f32_16x16x32_bf16(ah[mt], bh[nt], acc[mt][nt], 0, 0, 0);
                acc[mt][nt] = __builtin_amdgcn_mfma_f32_16x16x32_bf16(ah[mt], bl[nt], acc[mt][nt], 0, 0, 0);
                acc[mt][nt] = __builtin_amdgcn_mfma_f32_16x16x32_bf16(al[mt], bh[nt], acc[mt][nt], 0, 0, 0);
            }

        __syncthreads();
        if (!last) {
            STASH3();
            __syncthreads();
        }
    }

    #pragma unroll
    for (int nt = 0; nt < 4; ++nt) {
        int n = n0 + nt * 16 + ln;
        #pragma unroll
        for (int mt = 0; mt < 4; ++mt) {
            int mbase = m0 + wave * 64 + mt * 16 + q * 4;
            #pragma unroll
            for (int r = 0; r < 4; ++r) {
                int m = mbase + r;
                float v = acc[mt][nt][r];
                if (mode & 16) v *= (float)maskMul[(size_t)m * N + n];
                if (mode & 2)  v = fmaxf(v, 0.0f);
                if (mode & 4)  C[(size_t)m * ldc + n] = v;
            }
        }
    }
}

// ---------- zng: bf16 MFMA Jacobian chain ----------
// R15: 1 elem/block, 2 blocks/CU, 32x32x16 MFMA; A-operands from frag-packed
// weights (coalesced 1KB/wave-load vs R14's 64-line gather) + 2-deep A prefetch.
// __launch_bounds__(512,4) caps combined VGPR+AGPR at 128 for 4 waves/SIMD.
// Swizzle: logical 8-short chunk c of row rn stored at slot c^(rn&7).
// Fragment layouts (HW-verified, m74/m101): A/B row=lane&31, k=(lane>>5)*8+j;
// C col=lane&31, row=(reg&3)+8*(reg>>2)+4*(lane>>5).
__global__ __launch_bounds__(512, 4) void zng_kernel(
    const unsigned short* __restrict__ WhF,    // [2][16][32][64][8] frag-packed Wh1,Wh2
    const unsigned short* __restrict__ WoF,    // [2][32][64][8] frag-packed Wout
    const unsigned short* __restrict__ G0tb,   // [64][512] bf16 (G0 transposed)
    const unsigned char* __restrict__ mz1,
    const unsigned char* __restrict__ mz2,
    const unsigned char* __restrict__ mz3,
    float* __restrict__ out)                   // (4096,192), writes cols 128..191
{
    __shared__ __align__(16) unsigned short Rt[64 * 512]; // 65536 B, swizzled
    __shared__ unsigned char m2s[512];
    __shared__ unsigned char m3s[512];

    const int b0  = blockIdx.x;     // one batch element per block
    const int tid = threadIdx.x;

    m2s[tid] = mz2[(size_t)b0 * 512 + tid];
    m3s[tid] = mz3[(size_t)b0 * 512 + tid];

    // ---- setup: Rt = (mask1 (.) G0)^T, swizzled ----
    #pragma unroll
    for (int i = 0; i < 8; ++i) {
        int c = i * 512 + tid;             // 0..4095
        int n = c >> 6, ch = c & 63;
        int k = ch * 8;
        s8v g = *(const s8v*)(G0tb + n * 512 + k);
        const unsigned char* mm = mz1 + (size_t)b0 * 512 + k;
        unsigned int mlo = *(const unsigned int*)(mm);
        unsigned int mhi = *(const unsigned int*)(mm + 4);
        s8v r;
        #pragma unroll
        for (int j = 0; j < 4; ++j) r[j] = ((mlo >> (8 * j)) & 1) ? g[j] : (short)0;
        #pragma unroll
        for (int j = 0; j < 4; ++j) r[4 + j] = ((mhi >> (8 * j)) & 1) ? g[4 + j] : (short)0;
        *(s8v*)(&Rt[n * 512 + ((ch ^ (n & 7)) << 3)]) = r;
    }
    __syncthreads();

    const int lane = tid & 63, wave = tid >> 6;
    const int l31 = lane & 31, h = lane >> 5;
    const int l7 = l31 & 7;

    // ---- 2 chained layers: R <- mask (.) (Wh @ R) ----
    for (int s = 0; s < 2; ++s) {
        // frag-packed A: per-ks stride = 512 shorts; wave covers g32 = wave*2, wave*2+1
        const unsigned short* Ar0 = WhF + (size_t)s * 262144
                                  + (size_t)(wave * 2) * 16384 + lane * 8;
        const unsigned short* Ar1 = Ar0 + 16384;

        f16v acc[2][2];
        #pragma unroll
        for (int mt = 0; mt < 2; ++mt)
            #pragma unroll
            for (int nt = 0; nt < 2; ++nt)
                acc[mt][nt] = (f16v)(0.0f);

        // 2-deep A prefetch (L2 ~200cyc), 1-deep B prefetch (LDS)
        s8v a0A = *(const s8v*)(Ar0);
        s8v a1A = *(const s8v*)(Ar1);
        s8v a0B = *(const s8v*)(Ar0 + 512);
        s8v a1B = *(const s8v*)(Ar1 + 512);
        int cc0 = ((h ^ l7) << 3);
        s8v b0c = *(const s8v*)&Rt[l31 * 512 + cc0];
        s8v b1c = *(const s8v*)&Rt[(32 + l31) * 512 + cc0];

        #pragma unroll 4
        for (int ks = 0; ks < 32; ++ks) {
            int kf = ((ks + 2) & 31) * 512;           // wraps; redundant tail loads
            s8v a0N = *(const s8v*)(Ar0 + kf);
            s8v a1N = *(const s8v*)(Ar1 + kf);
            int cn = (((((ks + 1) & 31) * 2 + h) ^ l7) << 3);
            s8v b0n = *(const s8v*)&Rt[l31 * 512 + cn];
            s8v b1n = *(const s8v*)&Rt[(32 + l31) * 512 + cn];

            __builtin_amdgcn_s_setprio(1);
            acc[0][0] = __builtin_amdgcn_mfma_f32_32x32x16_bf16(a0A, b0c, acc[0][0], 0, 0, 0);
            acc[0][1] = __builtin_amdgcn_mfma_f32_32x32x16_bf16(a0A, b1c, acc[0][1], 0, 0, 0);
            acc[1][0] = __builtin_amdgcn_mfma_f32_32x32x16_bf16(a1A, b0c, acc[1][0], 0, 0, 0);
            acc[1][1] = __builtin_amdgcn_mfma_f32_32x32x16_bf16(a1A, b1c, acc[1][1], 0, 0, 0);
            __builtin_amdgcn_s_setprio(0);

            a0A = a0B; a0B = a0N;
            a1A = a1B; a1B = a1N;
            b0c = b0n; b1c = b1n;
        }
        __syncthreads();

        // ---- epilogue: mask, pack bf16, write new R^T (swizzled) ----
        const unsigned char* msk = (s == 0) ? m2s : m3s;
        #pragma unroll
        for (int mt = 0; mt < 2; ++mt) {
            #pragma unroll
            for (int g = 0; g < 4; ++g) {
                int mbase = wave * 64 + mt * 32 + g * 8 + h * 4;  // output row group
                int cw = wave * 8 + mt * 4 + g;                   // chunk = mbase>>3
                uchar4 mv = *(const uchar4*)&msk[mbase];
                unsigned char mb[4] = {mv.x, mv.y, mv.z, mv.w};
                #pragma unroll
                for (int nt = 0; nt < 2; ++nt) {
                    int rn = nt * 32 + l31;
                    s4v pk;
                    #pragma unroll
                    for (int r = 0; r < 4; ++r) {
                        float v = mb[r] ? acc[mt][nt][g * 4 + r] : 0.0f;
                        pk[r] = (short)f2bf(v);
                    }
                    *(s4v*)(&Rt[rn * 512 + ((cw ^ (rn & 7)) << 3) + h * 4]) = pk;
                }
            }
        }
        __syncthreads();
    }

    // ---- final: Wout @ R, row norms; waves 0-1 only (no barriers below) ----
    if (wave < 2) {
        const unsigned short* Wr = WoF + wave * 16384 + lane * 8;
        f16v a3[2];
        a3[0] = (f16v)(0.0f);
        a3[1] = (f16v)(0.0f);
        #pragma unroll 2
        for (int ks = 0; ks < 32; ++ks) {
            s8v af = *(const s8v*)(Wr + ks * 512);
            int cc = (((ks * 2 + h) ^ l7) << 3);
            s8v bb0 = *(const s8v*)&Rt[l31 * 512 + cc];
            s8v bb1 = *(const s8v*)&Rt[(32 + l31) * 512 + cc];
            a3[0] = __builtin_amdgcn_mfma_f32_32x32x16_bf16(af, bb0, a3[0], 0, 0, 0);
            a3[1] = __builtin_amdgcn_mfma_f32_32x32x16_bf16(af, bb1, a3[1], 0, 0, 0);
        }
        // per-lane: rows wave*32 + g*8 + h*4 + r, cols (nt*32 + l31)
        float sq[16];
        #pragma unroll
        for (int i = 0; i < 16; ++i) {
            float v0 = a3[0][i], v1 = a3[1][i];
            sq[i] = fmaf(v0, v0, v1 * v1);
        }
        #pragma unroll
        for (int off = 1; off < 32; off <<= 1)
            #pragma unroll
            for (int i = 0; i < 16; ++i)
                sq[i] += __shfl_xor(sq[i], off, 64);
        if (l31 == 0) {
            #pragma unroll
            for (int g = 0; g < 4; ++g)
                #pragma unroll
                for (int r = 0; r < 4; ++r)
                    out[(size_t)b0 * 192 + 128 + wave * 32 + g * 8 + h * 4 + r] = sqrtf(sq[g * 4 + r]);
        }
    }
}

// ---------- host ----------
extern "C" void kernel_launch(void* const* d_in, const int* in_sizes, int n_in,
                              void* d_out, int out_size, void* d_ws, size_t ws_size,
                              hipStream_t stream) {
    const float* x    = (const float*)d_in[0];
    const float* Win  = (const float*)d_in[1];
    const float* bin  = (const float*)d_in[2];
    const float* Wh   = (const float*)d_in[3];
    const float* bh   = (const float*)d_in[4];
    const float* Wout = (const float*)d_in[5];
    const float* bout = (const float*)d_in[6];
    float* out = (float*)d_out;

    char* ws = (char*)d_ws;
    unsigned short* whi  = (unsigned short*)(ws);                   // 1703936 B
    unsigned short* wlo  = (unsigned short*)(ws + 1703936);         // 1703936 B
    unsigned short* G0hi = (unsigned short*)(ws + 3407872);         // 65536 B
    unsigned short* G0lo = (unsigned short*)(ws + 3473408);         // 65536 B
    unsigned short* G0tb = (unsigned short*)(ws + 3538944);         // 65536 B
    unsigned char*  masks = (unsigned char*)(ws + 3604480);         // 6 * 2 MB
    unsigned char* mt1 = masks + 0 * 2097152;
    unsigned char* mt2 = masks + 1 * 2097152;
    unsigned char* mt3 = masks + 2 * 2097152;
    unsigned char* mz1 = masks + 3 * 2097152;
    unsigned char* mz2 = masks + 4 * 2097152;
    unsigned char* mz3 = masks + 5 * 2097152;
    float* bufs = (float*)(ws + 3604480 + 12582912);                // 4 x 8 MB
    float* tA = bufs + 0 * 2097152;
    float* tB = bufs + 1 * 2097152;
    float* zA = bufs + 2 * 2097152;
    float* zB = bufs + 3 * 2097152;
    unsigned short* WhF = (unsigned short*)(ws + 49741824);         // 1048576 B
    unsigned short* WoF = (unsigned short*)(ws + 50790400);         // 65536 B

    // hi/lo plane offsets (elems): [Win@0 | Wh0@32768 | Wh1@294912 | Wh2@557056 | Wout@819200]
    const unsigned short* WinH  = whi,          *WinL  = wlo;
    const unsigned short* Wh0H  = whi + 32768,  *Wh0L  = wlo + 32768;
    const unsigned short* Wh1H  = whi + 294912, *Wh1L  = wlo + 294912;
    const unsigned short* Wh2H  = whi + 557056, *Wh2L  = wlo + 557056;

    const float* Wh0 = Wh;
    const float* Wh1 = Wh + 262144;
    const float* Wh2 = Wh + 524288;
    const float* bh0 = bh, *bh1 = bh + 512, *bh2 = bh + 1024;

    conv_split<<<dim3(3328), dim3(256), 0, stream>>>(Win, Wh, Wout, whi, wlo);
    frag_pack<<<dim3(273), dim3(256), 0, stream>>>(whi, WhF, WoF);
    g0_kernel<<<dim3(512), dim3(64), 0, stream>>>(Wh0, Win, G0hi, G0lo, G0tb);

    auto gdual = [&](const float* X0, const float* X1, int ldx,
                     const float* W, const unsigned short* WH, const unsigned short* WL, int ldw,
                     const float* bias, float* C0, float* C1, int ldc,
                     unsigned char* mo0, unsigned char* mo1,
                     const unsigned char* mm0, const unsigned char* mm1,
                     int K, int N, int mode) {
        dim3 g(4096 / 128, N / 64, 2);
        gemm_dual<<<g, dim3(512), 0, stream>>>(X0, X1, ldx, W, ldw, WH, WL, bias,
                                               C0, C1, ldc, mo0, mo1, mm0, mm1, K, N, mode);
    };
    auto gemm1 = [&](const float* X, int ldx, const float* W, int ldw, const float* bias,
                     float* C, int ldc, unsigned char* mo, const unsigned char* mm,
                     int K, int N, int mode) {
        dim3 g(4096 / 128, N / 64, 1);
        gemm_nt<<<g, dim3(256), 0, stream>>>(X, ldx, W, ldw, bias, C, ldc, mo, mm, K, N, mode);
    };
    auto g3 = [&](const float* X, int ldx,
                  const unsigned short* WH, const unsigned short* WL, int ldw,
                  float* C, int ldc, const unsigned char* mm, int K, int N, int mode) {
        dim3 g(4096 / 128, N / 64, 1);
        gemm3<<<g, dim3(128), 0, stream>>>(X, ldx, WH, WL, ldw, C, ldc, mm, K, N, mode);
    };

    // ---- fused forward + delta chain (t fp32 ; z split-bf16 MFMA) ----
    gdual(x, x + 128, 192, Win, WinH, WinL, 64, bin, tA, zA, 512, 0, 0, 0, 0, 64, 512, 1 | 4);        // h0
    gdual(tA, zA, 512, Wh0, Wh0H, Wh0L, 512, bh0,   tB, zB, 512, 0, 0, 0, 0, 512, 512, 1 | 2 | 4);    // h1
    gdual(tB, zB, 512, Wh0, Wh0H, Wh0L, 512, bh0,   0, 0, 0, mt1, mz1, 0, 0, 512, 512, 1 | 8);        // delta1
    gdual(tB, zB, 512, Wh1, Wh1H, Wh1L, 512, bh1,   tA, zA, 512, 0, 0, 0, 0, 512, 512, 1 | 2 | 4);    // h2
    gdual(tA, zA, 512, Wh1, Wh1H, Wh1L, 512, bh1,   0, 0, 0, mt2, mz2, 0, 0, 512, 512, 1 | 8);        // delta2
    gdual(tA, zA, 512, Wh2, Wh2H, Wh2L, 512, bh2,   tB, zB, 512, 0, 0, 0, 0, 512, 512, 1 | 2 | 4);    // h3
    gdual(tB, zB, 512, Wh2, Wh2H, Wh2L, 512, bh2,   0, 0, 0, mt3, mz3, 0, 0, 512, 512, 1 | 8);        // delta3

    // ---- zng (z-branch Jacobian row norms), 1 elem/block, 2 blocks/CU ----
    zng_kernel<<<dim3(4096), dim3(512), 0, stream>>>(WhF, WoF, G0tb, mz1, mz2, mz3, out);

    // ---- h_out (t-branch forward output) — fp32 ----
    gemm1(tB, 512, Wout, 512, bout, out, 192, 0, 0, 512, 64, 1 | 4);                                  // cols 0..63

    // ---- h_dot chain: V = D (.) (W v) ----
    g3(x + 64, 192, G0hi, G0lo, 64, tA, 512, mt1, 64, 512, 4 | 16);                                   // V1 (split-bf16)
    g3(tA, 512, Wh1H, Wh1L, 512, zA, 512, mt2, 512, 512, 4 | 16);                                     // V2 (split-bf16)
    g3(zA, 512, Wh2H, Wh2L, 512, zB, 512, mt3, 512, 512, 4 | 16);                                     // V3 (split-bf16)
    gemm1(zB, 512, Wout, 512, 0, out + 64, 192, 0, 0, 512, 64, 4);                                    // h_dot (fp32)
}

// Round 3
// 759.224 us; speedup vs baseline: 1.3344x; 1.0551x over previous
//
#include <hip/hip_runtime.h>
#include <math.h>

typedef __attribute__((ext_vector_type(8))) short s8v;   // 8 x bf16
typedef __attribute__((ext_vector_type(4))) short s4v;   // 4 x bf16
typedef __attribute__((ext_vector_type(4))) float f4v;   // 4 x f32
typedef __attribute__((ext_vector_type(16))) float f16v; // 16 x f32

static __device__ __forceinline__ unsigned short f2bf(float f) {
    union { float f; unsigned int u; } v; v.f = f;
    unsigned int r = v.u + 0x7fffu + ((v.u >> 16) & 1u);   // RNE
    return (unsigned short)(r >> 16);
}
static __device__ __forceinline__ float bf2f(unsigned short h) {
    union { unsigned int u; float f; } t; t.u = ((unsigned int)h) << 16;
    return t.f;
}

// ---------- split all weights to bf16 hi/lo planes ----------
// layout: [Win(32768) | Wh0 | Wh1 | Wh2 (262144 each) | Wout(32768)] = 851968
__global__ void conv_split(const float* __restrict__ Win, const float* __restrict__ Wh,
                           const float* __restrict__ Wout,
                           unsigned short* __restrict__ whi, unsigned short* __restrict__ wlo) {
    int i = blockIdx.x * 256 + threadIdx.x;
    if (i >= 851968) return;
    float v;
    if (i < 32768)       v = Win[i];
    else if (i < 819200) v = Wh[i - 32768];
    else                 v = Wout[i - 819200];
    unsigned short h = f2bf(v);
    whi[i] = h;
    wlo[i] = f2bf(v - bf2f(h));
}

// ---------- pack zng weights into MFMA-fragment order (coalesced A-loads) ----------
// WhF[layer s][g32][ks][lane]: s8v = Wh_{1+s}[g32*32+(lane&31)][ks*16+(lane>>5)*8 .. +7]
// WoF[g32][ks][lane]:          s8v = Wout  [g32*32+(lane&31)][ks*16+(lane>>5)*8 .. +7]
__global__ void frag_pack(const unsigned short* __restrict__ whi,
                          unsigned short* __restrict__ WhF,   // [2][16][32][64][8] = 1 MB
                          unsigned short* __restrict__ WoF) { // [2][32][64][8] = 64 KB
    int i = blockIdx.x * 256 + threadIdx.x;     // fragment-slot (s8v) index
    if (i < 65536) {
        int lane = i & 63, ks = (i >> 6) & 31, g32 = (i >> 11) & 15, s = i >> 15;
        int row = g32 * 32 + (lane & 31);
        int k   = ks * 16 + (lane >> 5) * 8;
        const unsigned short* src = whi + 294912 + (size_t)s * 262144 + row * 512 + k;
        *(s8v*)(WhF + (size_t)i * 8) = *(const s8v*)src;
    } else if (i < 65536 + 4096) {
        int j = i - 65536;
        int lane = j & 63, ks = (j >> 6) & 31, g32 = j >> 11;
        int row = g32 * 32 + (lane & 31);
        int k   = ks * 16 + (lane >> 5) * 8;
        const unsigned short* src = whi + 819200 + row * 512 + k;
        *(s8v*)(WoF + (size_t)j * 8) = *(const s8v*)src;
    }
}

// ---------- G0 = Wh0 @ W_in (512x64): hi/lo planes + fragment-packed G0F for zng ----------
// G0F slot: value at (n=j, k=i) -> sl = ((i>>4)*2 + (j>>5))*64 + (j&31) + 32*((i>>3)&1), elem i&7
__global__ void g0_kernel(const float* __restrict__ Wh0, const float* __restrict__ Win,
                          unsigned short* __restrict__ G0hi, unsigned short* __restrict__ G0lo,
                          unsigned short* __restrict__ G0F) {
    int i = blockIdx.x;      // 0..511 (hidden)
    int j = threadIdx.x;     // 0..63  (d)
    float acc = 0.f;
    for (int k = 0; k < 512; ++k)
        acc = fmaf(Wh0[i * 512 + k], Win[k * 64 + j], acc);
    unsigned short h = f2bf(acc);
    G0hi[i * 64 + j] = h;
    G0lo[i * 64 + j] = f2bf(acc - bf2f(h));
    int sl = ((i >> 4) * 2 + (j >> 5)) * 64 + (j & 31) + 32 * ((i >> 3) & 1);
    G0F[(size_t)sl * 8 + (i & 7)] = h;
}

// ================= shared dual-GEMM bodies (R13/R15-validated code paths) =================

#define DF_LOAD(k0)                                                              \
    {                                                                            \
        _Pragma("unroll")                                                        \
        for (int r = 0; r < 2; ++r) {                                            \
            int idx = tid + r * 512;                                             \
            int row = idx >> 3, kq = (idx & 7) * 4;                              \
            xr[r] = *(const float4*)(X + (size_t)(m0 + row) * ldx + (k0) + kq);  \
        }                                                                        \
        {                                                                        \
            int row = tid >> 3, kq = (tid & 7) * 4;                              \
            wr = *(const float4*)(W + (size_t)(n0 + row) * ldw + (k0) + kq);     \
        }                                                                        \
    }
#define DF_STASH()                                                               \
    {                                                                            \
        _Pragma("unroll")                                                        \
        for (int r = 0; r < 2; ++r) {                                            \
            int idx = tid + r * 512;                                             \
            int row = idx >> 3, kq = (idx & 7) * 4;                              \
            Xs[kq + 0][row] = xr[r].x; Xs[kq + 1][row] = xr[r].y;                \
            Xs[kq + 2][row] = xr[r].z; Xs[kq + 3][row] = xr[r].w;                \
        }                                                                        \
        {                                                                        \
            int row = tid >> 3, kq = (tid & 7) * 4;                              \
            Ws[kq + 0][row] = wr.x; Ws[kq + 1][row] = wr.y;                      \
            Ws[kq + 2][row] = wr.z; Ws[kq + 3][row] = wr.w;                      \
        }                                                                        \
    }

static __device__ __forceinline__ void dual_fp32_body(
    unsigned char* lds, const float* __restrict__ X, int ldx,
    const float* __restrict__ W, int ldw, const float* __restrict__ bias,
    float* __restrict__ C, int ldc, unsigned char* __restrict__ maskOut,
    const unsigned char* __restrict__ maskMul, int K, int N, int mode)
{
    const int tid = threadIdx.x;
    const int m0 = blockIdx.x * 128;
    const int n0 = blockIdx.y * 64;
    float (*Xs)[132] = (float(*)[132])lds;                 // 16896 B
    float (*Ws)[68]  = (float(*)[68])(lds + 16896);        // 8704 B
    const int tx = tid & 15, ty = tid >> 4;                // ty 0..31
    float acc[4][4] = {};
    float4 xr[2], wr;

    DF_LOAD(0);
    DF_STASH();
    __syncthreads();

    for (int k0 = 0; k0 < K; k0 += 32) {
        bool last = (k0 + 32 >= K);
        if (!last) DF_LOAD(k0 + 32);
        #pragma unroll
        for (int kk = 0; kk < 32; ++kk) {
            float4 a0 = *(const float4*)&Xs[kk][ty * 4];
            float4 b0 = *(const float4*)&Ws[kk][tx * 4];
            float av[4] = {a0.x, a0.y, a0.z, a0.w};
            float bv[4] = {b0.x, b0.y, b0.z, b0.w};
            #pragma unroll
            for (int i = 0; i < 4; ++i)
                #pragma unroll
                for (int j = 0; j < 4; ++j)
                    acc[i][j] = fmaf(av[i], bv[j], acc[i][j]);
        }
        __syncthreads();
        if (!last) {
            DF_STASH();
            __syncthreads();
        }
    }

    float4 bb = {0, 0, 0, 0};
    if (mode & 1) bb = *(const float4*)(bias + n0 + tx * 4);
    const int c0 = n0 + tx * 4;
    #pragma unroll
    for (int i = 0; i < 4; ++i) {
        int r = m0 + ty * 4 + i;
        float v[4];
        #pragma unroll
        for (int j = 0; j < 4; ++j) {
            v[j] = acc[i][j];
            if (mode & 1) v[j] += ((const float*)&bb)[j];
        }
        if (mode & 8) {
            uchar4 mo;
            mo.x = v[0] > 0.0f; mo.y = v[1] > 0.0f; mo.z = v[2] > 0.0f; mo.w = v[3] > 0.0f;
            *(uchar4*)&maskOut[(size_t)r * N + c0] = mo;
        }
        if (mode & 16) {
            uchar4 mm = *(const uchar4*)&maskMul[(size_t)r * N + c0];
            v[0] *= mm.x; v[1] *= mm.y; v[2] *= mm.z; v[3] *= mm.w;
        }
        if (mode & 2) {
            #pragma unroll
            for (int j = 0; j < 4; ++j) v[j] = fmaxf(v[j], 0.0f);
        }
        if (mode & 4) {
            float4 st = {v[0], v[1], v[2], v[3]};
            *(float4*)(C + (size_t)r * ldc + c0) = st;
        }
    }
}
#undef DF_LOAD
#undef DF_STASH

#define DM_LOAD(k0)                                                                \
    {                                                                              \
        _Pragma("unroll")                                                          \
        for (int r = 0; r < 2; ++r) {                                              \
            int idx = tid + r * 512;                                               \
            int row = idx >> 3, kq = (idx & 7) * 4;                                \
            xr[r] = *(const float4*)(X + (size_t)(m0 + row) * ldx + (k0) + kq);    \
        }                                                                          \
        if (wload) {                                                               \
            int row = tid >> 2, kc = (tid & 3) * 8;                                \
            wh = *(const s8v*)(Whi + (size_t)(n0 + row) * ldw + (k0) + kc);        \
            wl = *(const s8v*)(Wlo + (size_t)(n0 + row) * ldw + (k0) + kc);        \
        }                                                                          \
    }
#define DM_STASH()                                                                 \
    {                                                                              \
        _Pragma("unroll")                                                          \
        for (int r = 0; r < 2; ++r) {                                              \
            int idx = tid + r * 512;                                               \
            int row = idx >> 3, kq = (idx & 7) * 4;                                \
            float a[4] = {xr[r].x, xr[r].y, xr[r].z, xr[r].w};                     \
            s4v hv, lv;                                                            \
            _Pragma("unroll")                                                      \
            for (int j = 0; j < 4; ++j) {                                          \
                unsigned short h = f2bf(a[j]);                                     \
                hv[j] = (short)h;                                                  \
                lv[j] = (short)f2bf(a[j] - bf2f(h));                               \
            }                                                                      \
            *(s4v*)&Xh[row * 40 + kq] = hv;                                        \
            *(s4v*)&Xl[row * 40 + kq] = lv;                                        \
        }                                                                          \
        if (wload) {                                                               \
            int row = tid >> 2, kc = (tid & 3) * 8;                                \
            *(s8v*)&Wsh[row * 40 + kc] = wh;                                       \
            *(s8v*)&Wsl[row * 40 + kc] = wl;                                       \
        }                                                                          \
    }

static __device__ __forceinline__ void dual_mfma_body(
    unsigned char* lds, const float* __restrict__ X, int ldx,
    const unsigned short* __restrict__ Whi, const unsigned short* __restrict__ Wlo, int ldw,
    const float* __restrict__ bias, float* __restrict__ C, int ldc,
    unsigned char* __restrict__ maskOut, const unsigned char* __restrict__ maskMul,
    int K, int N, int mode)
{
    const int tid = threadIdx.x;
    const int m0 = blockIdx.x * 128;
    const int n0 = blockIdx.y * 64;
    unsigned short* Xh  = (unsigned short*)lds;            // 128*40 = 10240 B
    unsigned short* Xl  = (unsigned short*)(lds + 10240);  // 10240 B
    unsigned short* Wsh = (unsigned short*)(lds + 20480);  // 5120 B
    unsigned short* Wsl = (unsigned short*)(lds + 25600);  // 5120 B

    const int wave = tid >> 6, lane = tid & 63;
    const int q = lane >> 4, ln = lane & 15;
    const int wm = (wave & 3) * 32;      // m-offset (0..96)
    const int wn = (wave >> 2) * 32;     // n-offset (0/32)

    f4v acc[2][2];
    #pragma unroll
    for (int mt = 0; mt < 2; ++mt)
        #pragma unroll
        for (int nt = 0; nt < 2; ++nt)
            acc[mt][nt] = (f4v)(0.0f);

    float4 xr[2];
    s8v wh, wl;
    const bool wload = (tid < 256);

    DM_LOAD(0);
    DM_STASH();
    __syncthreads();

    for (int k0 = 0; k0 < K; k0 += 32) {
        bool last = (k0 + 32 >= K);
        if (!last) DM_LOAD(k0 + 32);

        s8v ah[2], al[2], bh[2], bl[2];
        #pragma unroll
        for (int mt = 0; mt < 2; ++mt) {
            int rowm = wm + mt * 16 + ln;
            ah[mt] = *(const s8v*)&Xh[rowm * 40 + q * 8];
            al[mt] = *(const s8v*)&Xl[rowm * 40 + q * 8];
        }
        #pragma unroll
        for (int nt = 0; nt < 2; ++nt) {
            int rown = wn + nt * 16 + ln;
            bh[nt] = *(const s8v*)&Wsh[rown * 40 + q * 8];
            bl[nt] = *(const s8v*)&Wsl[rown * 40 + q * 8];
        }
        #pragma unroll
        for (int mt = 0; mt < 2; ++mt)
            #pragma unroll
            for (int nt = 0; nt < 2; ++nt) {
                acc[mt][nt] = __builtin_amdgcn_mfma_f32_16x16x32_bf16(ah[mt], bh[nt], acc[mt][nt], 0, 0, 0);
                acc[mt][nt] = __builtin_amdgcn_mfma_f32_16x16x32_bf16(ah[mt], bl[nt], acc[mt][nt], 0, 0, 0);
                acc[mt][nt] = __builtin_amdgcn_mfma_f32_16x16x32_bf16(al[mt], bh[nt], acc[mt][nt], 0, 0, 0);
            }

        __syncthreads();
        if (!last) {
            DM_STASH();
            __syncthreads();
        }
    }

    // epilogue: C-layout col=lane&15, row=q*4+r (m89-verified)
    #pragma unroll
    for (int nt = 0; nt < 2; ++nt) {
        int n = n0 + wn + nt * 16 + ln;
        float bv = (mode & 1) ? bias[n] : 0.0f;
        #pragma unroll
        for (int mt = 0; mt < 2; ++mt) {
            int mbase = m0 + wm + mt * 16 + q * 4;
            #pragma unroll
            for (int r = 0; r < 4; ++r) {
                int m = mbase + r;
                float v = acc[mt][nt][r] + bv;
                if (mode & 8)  maskOut[(size_t)m * N + n] = (v > 0.0f) ? 1 : 0;
                if (mode & 16) v *= (float)maskMul[(size_t)m * N + n];
                if (mode & 2)  v = fmaxf(v, 0.0f);
                if (mode & 4)  C[(size_t)m * ldc + n] = v;
            }
        }
    }
}
#undef DM_LOAD
#undef DM_STASH

// ======== dual GEMM (z=0 fp32 t-branch, z=1 split-bf16 MFMA z-branch) ========
__global__ __launch_bounds__(512) void gemm_dual(
    const float* __restrict__ X0, const float* __restrict__ X1, int ldx,
    const float* __restrict__ W, int ldw,
    const unsigned short* __restrict__ Whi, const unsigned short* __restrict__ Wlo,
    const float* __restrict__ bias,
    float* __restrict__ C0, float* __restrict__ C1, int ldc,
    unsigned char* __restrict__ mo0, unsigned char* __restrict__ mo1,
    const unsigned char* __restrict__ mm0, const unsigned char* __restrict__ mm1,
    int K, int N, int mode)
{
    __shared__ __align__(16) unsigned char lds[30720];
    if (blockIdx.z == 0)
        dual_fp32_body(lds, X0, ldx, W, ldw, bias, C0, ldc, mo0, mm0, K, N, mode);
    else
        dual_mfma_body(lds, X1, ldx, Whi, Wlo, ldw, bias, C1, ldc, mo1, mm1, K, N, mode);
}

// ======== fused dual4: z=0 t-h(next), z=1 z-h(next), z=2 t-delta(prev), z=3 z-delta(prev) ====
// delta_i and h_{i+1} consume the SAME inputs (h_i output) and are independent.
__global__ __launch_bounds__(512) void gemm_dual4(
    const float* __restrict__ X0, const float* __restrict__ X1, int ldx,
    const float* __restrict__ Wn, const float* __restrict__ Wd, int ldw,
    const unsigned short* __restrict__ WnH, const unsigned short* __restrict__ WnL,
    const unsigned short* __restrict__ WdH, const unsigned short* __restrict__ WdL,
    const float* __restrict__ bn, const float* __restrict__ bd,
    float* __restrict__ C0, float* __restrict__ C1, int ldc,
    unsigned char* __restrict__ mot, unsigned char* __restrict__ moz,
    int K, int N)
{
    __shared__ __align__(16) unsigned char lds[30720];
    int z = blockIdx.z;
    if (z == 0)
        dual_fp32_body(lds, X0, ldx, Wn, ldw, bn, C0, ldc, 0, 0, K, N, 1 | 2 | 4);
    else if (z == 2)
        dual_fp32_body(lds, X0, ldx, Wd, ldw, bd, 0, ldc, mot, 0, K, N, 1 | 8);
    else if (z == 1)
        dual_mfma_body(lds, X1, ldx, WnH, WnL, ldw, bn, C1, ldc, 0, 0, K, N, 1 | 2 | 4);
    else
        dual_mfma_body(lds, X1, ldx, WdH, WdL, ldw, bd, 0, ldc, moz, 0, K, N, 1 | 8);
}

// ======== fp32 GEMM 128x64 (R4-validated) — t-branch finals ========
__global__ __launch_bounds__(256) void gemm_nt(
    const float* __restrict__ X, int ldx,
    const float* __restrict__ W, int ldw,
    const float* __restrict__ bias,
    float* __restrict__ C, int ldc,
    unsigned char* __restrict__ maskOut,
    const unsigned char* __restrict__ maskMul,
    int K, int N, int mode)
{
    __shared__ float Xs[32][132];
    __shared__ float Ws[32][68];
    const int tid = threadIdx.x;
    const int m0 = blockIdx.x * 128;
    const int n0 = blockIdx.y * 64;
    const int tx = tid & 15, ty = tid >> 4;
    float acc[8][4] = {};
    float4 xr[4], wr[2];

    #define LOADCHUNK(k0)                                                        \
        {                                                                        \
            _Pragma("unroll")                                                    \
            for (int r = 0; r < 4; ++r) {                                        \
                int idx = tid + r * 256;                                         \
                int row = idx >> 3, kq = (idx & 7) * 4;                          \
                xr[r] = *(const float4*)(X + (size_t)(m0 + row) * ldx + (k0) + kq); \
            }                                                                    \
            _Pragma("unroll")                                                    \
            for (int r = 0; r < 2; ++r) {                                        \
                int idx = tid + r * 256;                                         \
                int row = idx >> 3, kq = (idx & 7) * 4;                          \
                wr[r] = *(const float4*)(W + (size_t)(n0 + row) * ldw + (k0) + kq); \
            }                                                                    \
        }
    #define STASH()                                                              \
        {                                                                        \
            _Pragma("unroll")                                                    \
            for (int r = 0; r < 4; ++r) {                                        \
                int idx = tid + r * 256;                                         \
                int row = idx >> 3, kq = (idx & 7) * 4;                          \
                Xs[kq + 0][row] = xr[r].x; Xs[kq + 1][row] = xr[r].y;            \
                Xs[kq + 2][row] = xr[r].z; Xs[kq + 3][row] = xr[r].w;            \
            }                                                                    \
            _Pragma("unroll")                                                    \
            for (int r = 0; r < 2; ++r) {                                        \
                int idx = tid + r * 256;                                         \
                int row = idx >> 3, kq = (idx & 7) * 4;                          \
                Ws[kq + 0][row] = wr[r].x; Ws[kq + 1][row] = wr[r].y;            \
                Ws[kq + 2][row] = wr[r].z; Ws[kq + 3][row] = wr[r].w;            \
            }                                                                    \
        }

    LOADCHUNK(0);
    STASH();
    __syncthreads();

    for (int k0 = 0; k0 < K; k0 += 32) {
        bool last = (k0 + 32 >= K);
        if (!last) LOADCHUNK(k0 + 32);
        #pragma unroll
        for (int kk = 0; kk < 32; ++kk) {
            float4 a0 = *(const float4*)&Xs[kk][ty * 4];
            float4 a1 = *(const float4*)&Xs[kk][64 + ty * 4];
            float4 b0 = *(const float4*)&Ws[kk][tx * 4];
            float av[8] = {a0.x, a0.y, a0.z, a0.w, a1.x, a1.y, a1.z, a1.w};
            float bv[4] = {b0.x, b0.y, b0.z, b0.w};
            #pragma unroll
            for (int i = 0; i < 8; ++i)
                #pragma unroll
                for (int j = 0; j < 4; ++j)
                    acc[i][j] = fmaf(av[i], bv[j], acc[i][j]);
        }
        __syncthreads();
        if (!last) {
            STASH();
            __syncthreads();
        }
    }

    float4 bb = {0, 0, 0, 0};
    if (mode & 1) bb = *(const float4*)(bias + n0 + tx * 4);
    const int c0 = n0 + tx * 4;
    #pragma unroll
    for (int i = 0; i < 8; ++i) {
        int r = m0 + ((i < 4) ? (ty * 4 + i) : (64 + ty * 4 + (i - 4)));
        float v[4];
        #pragma unroll
        for (int j = 0; j < 4; ++j) {
            v[j] = acc[i][j];
            if (mode & 1) v[j] += ((const float*)&bb)[j];
        }
        if (mode & 8) {
            uchar4 mo;
            mo.x = v[0] > 0.0f; mo.y = v[1] > 0.0f; mo.z = v[2] > 0.0f; mo.w = v[3] > 0.0f;
            *(uchar4*)&maskOut[(size_t)r * N + c0] = mo;
        }
        if (mode & 16) {
            uchar4 mm = *(const uchar4*)&maskMul[(size_t)r * N + c0];
            v[0] *= mm.x; v[1] *= mm.y; v[2] *= mm.z; v[3] *= mm.w;
        }
        if (mode & 2) {
            #pragma unroll
            for (int j = 0; j < 4; ++j) v[j] = fmaxf(v[j], 0.0f);
        }
        if (mode & 4) {
            float4 st = {v[0], v[1], v[2], v[3]};
            *(float4*)(C + (size_t)r * ldc + c0) = st;
        }
    }
}

// ======== split-bf16 MFMA GEMM (R9-validated) — V1,V2,V3 ========
__global__ __launch_bounds__(128) void gemm3(
    const float* __restrict__ X, int ldx,
    const unsigned short* __restrict__ Whi, const unsigned short* __restrict__ Wlo, int ldw,
    float* __restrict__ C, int ldc,
    const unsigned char* __restrict__ maskMul,
    int K, int N, int mode)
{
    __shared__ __align__(16) unsigned short Xh[128 * 40];
    __shared__ __align__(16) unsigned short Xl[128 * 40];
    __shared__ __align__(16) unsigned short Wsh[64 * 40];
    __shared__ __align__(16) unsigned short Wsl[64 * 40];

    const int tid = threadIdx.x;
    const int m0 = blockIdx.x * 128;
    const int n0 = blockIdx.y * 64;
    const int wave = tid >> 6, lane = tid & 63;
    const int q = lane >> 4, ln = lane & 15;

    f4v acc[4][4];
    #pragma unroll
    for (int mt = 0; mt < 4; ++mt)
        #pragma unroll
        for (int nt = 0; nt < 4; ++nt)
            acc[mt][nt] = (f4v)(0.0f);

    float4 xr[8];
    s8v wh[2], wl[2];

    #define LOADC3(k0)                                                             \
        {                                                                          \
            _Pragma("unroll")                                                      \
            for (int r = 0; r < 8; ++r) {                                          \
                int idx = tid + r * 128;                                           \
                int row = idx >> 3, kq = (idx & 7) * 4;                            \
                xr[r] = *(const float4*)(X + (size_t)(m0 + row) * ldx + (k0) + kq); \
            }                                                                      \
            _Pragma("unroll")                                                      \
            for (int r = 0; r < 2; ++r) {                                          \
                int idx = tid + r * 128;                                           \
                int row = idx >> 2, kc = (idx & 3) * 8;                            \
                wh[r] = *(const s8v*)(Whi + (size_t)(n0 + row) * ldw + (k0) + kc); \
                wl[r] = *(const s8v*)(Wlo + (size_t)(n0 + row) * ldw + (k0) + kc); \
            }                                                                      \
        }
    #define STASH3()                                                               \
        {                                                                          \
            _Pragma("unroll")                                                      \
            for (int r = 0; r < 8; ++r) {                                          \
                int idx = tid + r * 128;                                           \
                int row = idx >> 3, kq = (idx & 7) * 4;                            \
                float a[4] = {xr[r].x, xr[r].y, xr[r].z, xr[r].w};                 \
                s4v hv, lv;                                                        \
                _Pragma("unroll")                                                  \
                for (int j = 0; j < 4; ++j) {                                      \
                    unsigned short h = f2bf(a[j]);                                 \
                    hv[j] = (short)h;                                              \
                    lv[j] = (short)f2bf(a[j] - bf2f(h));                           \
                }                                                                  \
                *(s4v*)&Xh[row * 40 + kq] = hv;                                    \
                *(s4v*)&Xl[row * 40 + kq] = lv;                                    \
            }                                                                      \
            _Pragma("unroll")                                                      \
            for (int r = 0; r < 2; ++r) {                                          \
                int idx = tid + r * 128;                                           \
                int row = idx >> 2, kc = (idx & 3) * 8;                            \
                *(s8v*)&Wsh[row * 40 + kc] = wh[r];                                \
                *(s8v*)&Wsl[row * 40 + kc] = wl[r];                                \
            }                                                                      \
        }

    LOADC3(0);
    STASH3();
    __syncthreads();

    for (int k0 = 0; k0 < K; k0 += 32) {
        bool last = (k0 + 32 >= K);
        if (!last) LOADC3(k0 + 32);

        s8v ah[4], al[4], bh[4], bl[4];
        #pragma unroll
        for (int mt = 0; mt < 4; ++mt) {
            int rowm = wave * 64 + mt * 16 + ln;
            ah[mt] = *(const s8v*)&Xh[rowm * 40 + q * 8];
            al[mt] = *(const s8v*)&Xl[rowm * 40 + q * 8];
        }
        #pragma unroll
        for (int nt = 0; nt < 4; ++nt) {
            int rown = nt * 16 + ln;
            bh[nt] = *(const s8v*)&Wsh[rown * 40 + q * 8];
            bl[nt] = *(const s8v*)&Wsl[rown * 40 + q * 8];
        }
        #pragma unroll
        for (int mt = 0; mt < 4; ++mt)
            #pragma unroll
            for (int nt = 0; nt < 4; ++nt) {
                acc[mt][nt] = __builtin_amdgcn_mfma_f32_16x16x32_bf16(ah[mt], bh[nt], acc[mt][nt], 0, 0, 0);
                acc[mt][nt] = __builtin_amdgcn_mfma_f32_16x16x32_bf16(ah[mt], bl[nt], acc[mt][nt], 0, 0, 0);
                acc[mt][nt] = __builtin_amdgcn_mfma_f32_16x16x32_bf16(al[mt], bh[nt], acc[mt][nt], 0, 0, 0);
            }

        __syncthreads();
        if (!last) {
            STASH3();
            __syncthreads();
        }
    }

    #pragma unroll
    for (int nt = 0; nt < 4; ++nt) {
        int n = n0 + nt * 16 + ln;
        #pragma unroll
        for (int mt = 0; mt < 4; ++mt) {
            int mbase = m0 + wave * 64 + mt * 16 + q * 4;
            #pragma unroll
            for (int r = 0; r < 4; ++r) {
                int m = mbase + r;
                float v = acc[mt][nt][r];
                if (mode & 16) v *= (float)maskMul[(size_t)m * N + n];
                if (mode & 2)  v = fmaxf(v, 0.0f);
                if (mode & 4)  C[(size_t)m * ldc + n] = v;
            }
        }
    }
}

// ---------- zng: bf16 MFMA Jacobian chain ----------
// R16: Rt stored in MFMA-FRAGMENT order (RtF[ks][half][lane][8]) — every B-read
// is a wave-contiguous 1KB ds_read_b128 (no bank aliasing across rows), epilogue
// writes are contiguous 512B spans, setup reads fragment-packed G0F coalesced.
// Eliminates the structural 4-way conflict of the row-major+XOR layout (2.36e7).
// 1 elem/block, 2 blocks/CU; __launch_bounds__(512,4) caps VGPR+AGPR at 128.
// Fragment layouts (HW-verified, m74/m101): A/B row|col=lane&31, k=(lane>>5)*8+j;
// C col=lane&31, row=(reg&3)+8*(reg>>2)+4*(lane>>5).
__global__ __launch_bounds__(512, 4) void zng_kernel(
    const unsigned short* __restrict__ WhF,    // [2][16][32][64][8] frag-packed Wh1,Wh2
    const unsigned short* __restrict__ WoF,    // [2][32][64][8] frag-packed Wout
    const unsigned short* __restrict__ G0F,    // [32][2][64][8] frag-packed G0
    const unsigned char* __restrict__ mz1,
    const unsigned char* __restrict__ mz2,
    const unsigned char* __restrict__ mz3,
    float* __restrict__ out)                   // (4096,192), writes cols 128..191
{
    __shared__ __align__(16) unsigned short RtF[32 * 2 * 64 * 8]; // 65536 B, fragment order
    __shared__ unsigned char m2s[512];
    __shared__ unsigned char m3s[512];

    const int b0  = blockIdx.x;     // one batch element per block
    const int tid = threadIdx.x;

    m2s[tid] = mz2[(size_t)b0 * 512 + tid];
    m3s[tid] = mz3[(size_t)b0 * 512 + tid];

    // ---- setup: RtF = frag(mask1 (.) G0^T); coalesced read + linear LDS write ----
    #pragma unroll
    for (int it = 0; it < 8; ++it) {
        int sl = it * 512 + tid;           // fragment slot 0..4095
        int ls = sl & 63;                  // lane within fragment
        int ks = sl >> 7;                  // k-step
        int k0 = ks * 16 + (ls >> 5) * 8;  // first k of this lane's 8 elems
        s8v g = *(const s8v*)(G0F + (size_t)sl * 8);
        const unsigned char* mm = mz1 + (size_t)b0 * 512 + k0;
        unsigned int mlo = *(const unsigned int*)(mm);
        unsigned int mhi = *(const unsigned int*)(mm + 4);
        s8v r;
        #pragma unroll
        for (int j = 0; j < 4; ++j) r[j] = ((mlo >> (8 * j)) & 1) ? g[j] : (short)0;
        #pragma unroll
        for (int j = 0; j < 4; ++j) r[4 + j] = ((mhi >> (8 * j)) & 1) ? g[4 + j] : (short)0;
        *(s8v*)(&RtF[(size_t)sl * 8]) = r;
    }
    __syncthreads();

    const int lane = tid & 63, wave = tid >> 6;
    const int l31 = lane & 31, h = lane >> 5;

    // ---- 2 chained layers: R <- mask (.) (Wh @ R) ----
    for (int s = 0; s < 2; ++s) {
        const unsigned short* Ar0 = WhF + (size_t)s * 262144
                                  + (size_t)(wave * 2) * 16384 + lane * 8;
        const unsigned short* Ar1 = Ar0 + 16384;

        f16v acc[2][2];
        #pragma unroll
        for (int mt = 0; mt < 2; ++mt)
            #pragma unroll
            for (int nt = 0; nt < 2; ++nt)
                acc[mt][nt] = (f16v)(0.0f);

        // 2-deep A prefetch (L2 ~200cyc), 1-deep B prefetch (LDS)
        s8v a0A = *(const s8v*)(Ar0);
        s8v a1A = *(const s8v*)(Ar1);
        s8v a0B = *(const s8v*)(Ar0 + 512);
        s8v a1B = *(const s8v*)(Ar1 + 512);
        s8v b0c = *(const s8v*)&RtF[lane * 8];
        s8v b1c = *(const s8v*)&RtF[512 + lane * 8];

        #pragma unroll 4
        for (int ks = 0; ks < 32; ++ks) {
            int kf = ((ks + 2) & 31) * 512;           // A: wraps; redundant tail loads
            s8v a0N = *(const s8v*)(Ar0 + kf);
            s8v a1N = *(const s8v*)(Ar1 + kf);
            int kb = ((ks + 1) & 31) * 1024;          // B: fragment-linear
            s8v b0n = *(const s8v*)&RtF[kb + lane * 8];
            s8v b1n = *(const s8v*)&RtF[kb + 512 + lane * 8];

            __builtin_amdgcn_s_setprio(1);
            acc[0][0] = __builtin_amdgcn_mfma_f32_32x32x16_bf16(a0A, b0c, acc[0][0], 0, 0, 0);
            acc[0][1] = __builtin_amdgcn_mfma_f32_32x32x16_bf16(a0A, b1c, acc[0][1], 0, 0, 0);
            acc[1][0] = __builtin_amdgcn_mfma_f32_32x32x16_bf16(a1A, b0c, acc[1][0], 0, 0, 0);
            acc[1][1] = __builtin_amdgcn_mfma_f32_32x32x16_bf16(a1A, b1c, acc[1][1], 0, 0, 0);
            __builtin_amdgcn_s_setprio(0);

            a0A = a0B; a0B = a0N;
            a1A = a1B; a1B = a1N;
            b0c = b0n; b1c = b1n;
        }
        __syncthreads();

        // ---- epilogue: mask, pack bf16, write new RtF (fragment order, conflict-free) ----
        const unsigned char* msk = (s == 0) ? m2s : m3s;
        #pragma unroll
        for (int mt = 0; mt < 2; ++mt) {
            #pragma unroll
            for (int g = 0; g < 4; ++g) {
                int kk = wave * 64 + mt * 32 + g * 8 + h * 4;   // output k-row base
                int ks = wave * 4 + mt * 2 + (g >> 1);
                int khalf = g & 1;
                uchar4 mv = *(const uchar4*)&msk[kk];
                unsigned char mb[4] = {mv.x, mv.y, mv.z, mv.w};
                #pragma unroll
                for (int nt = 0; nt < 2; ++nt) {
                    s4v pk;
                    #pragma unroll
                    for (int r = 0; r < 4; ++r) {
                        float v = mb[r] ? acc[mt][nt][g * 4 + r] : 0.0f;
                        pk[r] = (short)f2bf(v);
                    }
                    *(s4v*)(&RtF[(ks * 2 + nt) * 512 + (l31 + 32 * khalf) * 8 + h * 4]) = pk;
                }
            }
        }
        __syncthreads();
    }

    // ---- final: Wout @ R, row norms; waves 0-1 only (no barriers below) ----
    if (wave < 2) {
        const unsigned short* Wr = WoF + wave * 16384 + lane * 8;
        f16v a3[2];
        a3[0] = (f16v)(0.0f);
        a3[1] = (f16v)(0.0f);
        #pragma unroll 2
        for (int ks = 0; ks < 32; ++ks) {
            s8v af = *(const s8v*)(Wr + ks * 512);
            s8v bb0 = *(const s8v*)&RtF[ks * 1024 + lane * 8];
            s8v bb1 = *(const s8v*)&RtF[ks * 1024 + 512 + lane * 8];
            a3[0] = __builtin_amdgcn_mfma_f32_32x32x16_bf16(af, bb0, a3[0], 0, 0, 0);
            a3[1] = __builtin_amdgcn_mfma_f32_32x32x16_bf16(af, bb1, a3[1], 0, 0, 0);
        }
        // per-lane: rows wave*32 + g*8 + h*4 + r, cols (nt*32 + l31)
        float sq[16];
        #pragma unroll
        for (int i = 0; i < 16; ++i) {
            float v0 = a3[0][i], v1 = a3[1][i];
            sq[i] = fmaf(v0, v0, v1 * v1);
        }
        #pragma unroll
        for (int off = 1; off < 32; off <<= 1)
            #pragma unroll
            for (int i = 0; i < 16; ++i)
                sq[i] += __shfl_xor(sq[i], off, 64);
        if (l31 == 0) {
            #pragma unroll
            for (int g = 0; g < 4; ++g)
                #pragma unroll
                for (int r = 0; r < 4; ++r)
                    out[(size_t)b0 * 192 + 128 + wave * 32 + g * 8 + h * 4 + r] = sqrtf(sq[g * 4 + r]);
        }
    }
}

// ---------- host ----------
extern "C" void kernel_launch(void* const* d_in, const int* in_sizes, int n_in,
                              void* d_out, int out_size, void* d_ws, size_t ws_size,
                              hipStream_t stream) {
    const float* x    = (const float*)d_in[0];
    const float* Win  = (const float*)d_in[1];
    const float* bin  = (const float*)d_in[2];
    const float* Wh   = (const float*)d_in[3];
    const float* bh   = (const float*)d_in[4];
    const float* Wout = (const float*)d_in[5];
    const float* bout = (const float*)d_in[6];
    float* out = (float*)d_out;

    char* ws = (char*)d_ws;
    unsigned short* whi  = (unsigned short*)(ws);                   // 1703936 B
    unsigned short* wlo  = (unsigned short*)(ws + 1703936);         // 1703936 B
    unsigned short* G0hi = (unsigned short*)(ws + 3407872);         // 65536 B
    unsigned short* G0lo = (unsigned short*)(ws + 3473408);         // 65536 B
    unsigned short* G0F  = (unsigned short*)(ws + 3538944);         // 65536 B (frag-packed)
    unsigned char*  masks = (unsigned char*)(ws + 3604480);         // 6 * 2 MB
    unsigned char* mt1 = masks + 0 * 2097152;
    unsigned char* mt2 = masks + 1 * 2097152;
    unsigned char* mt3 = masks + 2 * 2097152;
    unsigned char* mz1 = masks + 3 * 2097152;
    unsigned char* mz2 = masks + 4 * 2097152;
    unsigned char* mz3 = masks + 5 * 2097152;
    float* bufs = (float*)(ws + 3604480 + 12582912);                // 4 x 8 MB
    float* tA = bufs + 0 * 2097152;
    float* tB = bufs + 1 * 2097152;
    float* zA = bufs + 2 * 2097152;
    float* zB = bufs + 3 * 2097152;
    unsigned short* WhF = (unsigned short*)(ws + 49741824);         // 1048576 B
    unsigned short* WoF = (unsigned short*)(ws + 50790400);         // 65536 B

    // hi/lo plane offsets (elems): [Win@0 | Wh0@32768 | Wh1@294912 | Wh2@557056 | Wout@819200]
    const unsigned short* WinH  = whi,          *WinL  = wlo;
    const unsigned short* Wh0H  = whi + 32768,  *Wh0L  = wlo + 32768;
    const unsigned short* Wh1H  = whi + 294912, *Wh1L  = wlo + 294912;
    const unsigned short* Wh2H  = whi + 557056, *Wh2L  = wlo + 557056;

    const float* Wh0 = Wh;
    const float* Wh1 = Wh + 262144;
    const float* Wh2 = Wh + 524288;
    const float* bh0 = bh, *bh1 = bh + 512, *bh2 = bh + 1024;

    conv_split<<<dim3(3328), dim3(256), 0, stream>>>(Win, Wh, Wout, whi, wlo);
    frag_pack<<<dim3(273), dim3(256), 0, stream>>>(whi, WhF, WoF);
    g0_kernel<<<dim3(512), dim3(64), 0, stream>>>(Wh0, Win, G0hi, G0lo, G0F);

    auto gdual = [&](const float* X0, const float* X1, int ldx,
                     const float* W, const unsigned short* WH, const unsigned short* WL, int ldw,
                     const float* bias, float* C0, float* C1, int ldc,
                     unsigned char* mo0, unsigned char* mo1,
                     const unsigned char* mm0, const unsigned char* mm1,
                     int K, int N, int mode) {
        dim3 g(4096 / 128, N / 64, 2);
        gemm_dual<<<g, dim3(512), 0, stream>>>(X0, X1, ldx, W, ldw, WH, WL, bias,
                                               C0, C1, ldc, mo0, mo1, mm0, mm1, K, N, mode);
    };
    auto gdual4 = [&](const float* X0, const float* X1,
                      const float* Wn, const unsigned short* WnH, const unsigned short* WnL,
                      const float* Wd, const unsigned short* WdH, const unsigned short* WdL,
                      const float* bn, const float* bd,
                      float* C0, float* C1,
                      unsigned char* mot, unsigned char* moz) {
        dim3 g(4096 / 128, 8, 4);
        gemm_dual4<<<g, dim3(512), 0, stream>>>(X0, X1, 512, Wn, Wd, 512, WnH, WnL, WdH, WdL,
                                                bn, bd, C0, C1, 512, mot, moz, 512, 512);
    };
    auto gemm1 = [&](const float* X, int ldx, const float* W, int ldw, const float* bias,
                     float* C, int ldc, unsigned char* mo, const unsigned char* mm,
                     int K, int N, int mode) {
        dim3 g(4096 / 128, N / 64, 1);
        gemm_nt<<<g, dim3(256), 0, stream>>>(X, ldx, W, ldw, bias, C, ldc, mo, mm, K, N, mode);
    };
    auto g3 = [&](const float* X, int ldx,
                  const unsigned short* WH, const unsigned short* WL, int ldw,
                  float* C, int ldc, const unsigned char* mm, int K, int N, int mode) {
        dim3 g(4096 / 128, N / 64, 1);
        gemm3<<<g, dim3(128), 0, stream>>>(X, ldx, WH, WL, ldw, C, ldc, mm, K, N, mode);
    };

    // ---- fused forward + delta chain (t fp32 ; z split-bf16 MFMA) ----
    gdual(x, x + 128, 192, Win, WinH, WinL, 64, bin, tA, zA, 512, 0, 0, 0, 0, 64, 512, 1 | 4);        // h0
    gdual(tA, zA, 512, Wh0, Wh0H, Wh0L, 512, bh0,   tB, zB, 512, 0, 0, 0, 0, 512, 512, 1 | 2 | 4);    // h1
    gdual4(tB, zB, Wh1, Wh1H, Wh1L, Wh0, Wh0H, Wh0L, bh1, bh0, tA, zA, mt1, mz1);                     // h2 + delta1
    gdual4(tA, zA, Wh2, Wh2H, Wh2L, Wh1, Wh1H, Wh1L, bh2, bh1, tB, zB, mt2, mz2);                     // h3 + delta2
    gdual(tB, zB, 512, Wh2, Wh2H, Wh2L, 512, bh2,   0, 0, 0, mt3, mz3, 0, 0, 512, 512, 1 | 8);        // delta3

    // ---- zng (z-branch Jacobian row norms), 1 elem/block, 2 blocks/CU ----
    zng_kernel<<<dim3(4096), dim3(512), 0, stream>>>(WhF, WoF, G0F, mz1, mz2, mz3, out);

    // ---- h_out (t-branch forward output) — fp32 ----
    gemm1(tB, 512, Wout, 512, bout, out, 192, 0, 0, 512, 64, 1 | 4);                                  // cols 0..63

    // ---- h_dot chain: V = D (.) (W v) ----
    g3(x + 64, 192, G0hi, G0lo, 64, tA, 512, mt1, 64, 512, 4 | 16);                                   // V1 (split-bf16)
    g3(tA, 512, Wh1H, Wh1L, 512, zA, 512, mt2, 512, 512, 4 | 16);                                     // V2 (split-bf16)
    g3(zA, 512, Wh2H, Wh2L, 512, zB, 512, mt3, 512, 512, 4 | 16);                                     // V3 (split-bf16)
    gemm1(zB, 512, Wout, 512, 0, out + 64, 192, 0, 0, 512, 64, 4);                                    // h_dot (fp32)
}

// Round 5
// 669.666 us; speedup vs baseline: 1.5129x; 1.1337x over previous
//
#include <hip/hip_runtime.h>
#include <math.h>

typedef __attribute__((ext_vector_type(8))) short s8v;   // 8 x bf16
typedef __attribute__((ext_vector_type(4))) short s4v;   // 4 x bf16
typedef __attribute__((ext_vector_type(4))) float f4v;   // 4 x f32
typedef __attribute__((ext_vector_type(16))) float f16v; // 16 x f32

static __device__ __forceinline__ unsigned short f2bf(float f) {
    union { float f; unsigned int u; } v; v.f = f;
    unsigned int r = v.u + 0x7fffu + ((v.u >> 16) & 1u);   // RNE
    return (unsigned short)(r >> 16);
}
static __device__ __forceinline__ float bf2f(unsigned short h) {
    union { unsigned int u; float f; } t; t.u = ((unsigned int)h) << 16;
    return t.f;
}

// ---------- split all weights to bf16 hi/lo planes ----------
// layout: [Win(32768) | Wh0 | Wh1 | Wh2 (262144 each) | Wout(32768)] = 851968
__global__ void conv_split(const float* __restrict__ Win, const float* __restrict__ Wh,
                           const float* __restrict__ Wout,
                           unsigned short* __restrict__ whi, unsigned short* __restrict__ wlo) {
    int i = blockIdx.x * 256 + threadIdx.x;
    if (i >= 851968) return;
    float v;
    if (i < 32768)       v = Win[i];
    else if (i < 819200) v = Wh[i - 32768];
    else                 v = Wout[i - 819200];
    unsigned short h = f2bf(v);
    whi[i] = h;
    wlo[i] = f2bf(v - bf2f(h));
}

// ---------- pack zng weights into MFMA-fragment order (coalesced A-loads) ----------
__global__ void frag_pack(const unsigned short* __restrict__ whi,
                          unsigned short* __restrict__ WhF,   // [2][16][32][64][8] = 1 MB
                          unsigned short* __restrict__ WoF) { // [2][32][64][8] = 64 KB
    int i = blockIdx.x * 256 + threadIdx.x;     // fragment-slot (s8v) index
    if (i < 65536) {
        int lane = i & 63, ks = (i >> 6) & 31, g32 = (i >> 11) & 15, s = i >> 15;
        int row = g32 * 32 + (lane & 31);
        int k   = ks * 16 + (lane >> 5) * 8;
        const unsigned short* src = whi + 294912 + (size_t)s * 262144 + row * 512 + k;
        *(s8v*)(WhF + (size_t)i * 8) = *(const s8v*)src;
    } else if (i < 65536 + 4096) {
        int j = i - 65536;
        int lane = j & 63, ks = (j >> 6) & 31, g32 = j >> 11;
        int row = g32 * 32 + (lane & 31);
        int k   = ks * 16 + (lane >> 5) * 8;
        const unsigned short* src = whi + 819200 + row * 512 + k;
        *(s8v*)(WoF + (size_t)j * 8) = *(const s8v*)src;
    }
}

// ---------- G0 = Wh0 @ W_in (512x64): hi/lo planes + fragment-packed G0F for zng ----------
__global__ void g0_kernel(const float* __restrict__ Wh0, const float* __restrict__ Win,
                          unsigned short* __restrict__ G0hi, unsigned short* __restrict__ G0lo,
                          unsigned short* __restrict__ G0F) {
    int i = blockIdx.x;      // 0..511 (hidden)
    int j = threadIdx.x;     // 0..63  (d)
    float acc = 0.f;
    for (int k = 0; k < 512; ++k)
        acc = fmaf(Wh0[i * 512 + k], Win[k * 64 + j], acc);
    unsigned short h = f2bf(acc);
    G0hi[i * 64 + j] = h;
    G0lo[i * 64 + j] = f2bf(acc - bf2f(h));
    int sl = ((i >> 4) * 2 + (j >> 5)) * 64 + (j & 31) + 32 * ((i >> 3) & 1);
    G0F[(size_t)sl * 8 + (i & 7)] = h;
}

// ================= shared GEMM bodies =================
// fp32 body: mask-PRODUCING chain must stay fp32 (R17 lesson: 3-term bf16 preact
// error ~1.7e-4 flips ~900 masks -> h_dot absmax 0.14).

#define DF_LOAD(k0)                                                              \
    {                                                                            \
        _Pragma("unroll")                                                        \
        for (int r = 0; r < 2; ++r) {                                            \
            int idx = tid + r * 512;                                             \
            int row = idx >> 3, kq = (idx & 7) * 4;                              \
            xr[r] = *(const float4*)(X + (size_t)(m0 + row) * ldx + (k0) + kq);  \
        }                                                                        \
        {                                                                        \
            int row = tid >> 3, kq = (tid & 7) * 4;                              \
            wr = *(const float4*)(W + (size_t)(n0 + row) * ldw + (k0) + kq);     \
        }                                                                        \
    }
#define DF_STASH()                                                               \
    {                                                                            \
        _Pragma("unroll")                                                        \
        for (int r = 0; r < 2; ++r) {                                            \
            int idx = tid + r * 512;                                             \
            int row = idx >> 3, kq = (idx & 7) * 4;                              \
            Xs[kq + 0][row] = xr[r].x; Xs[kq + 1][row] = xr[r].y;                \
            Xs[kq + 2][row] = xr[r].z; Xs[kq + 3][row] = xr[r].w;                \
        }                                                                        \
        {                                                                        \
            int row = tid >> 3, kq = (tid & 7) * 4;                              \
            Ws[kq + 0][row] = wr.x; Ws[kq + 1][row] = wr.y;                      \
            Ws[kq + 2][row] = wr.z; Ws[kq + 3][row] = wr.w;                      \
        }                                                                        \
    }

static __device__ __forceinline__ void dual_fp32_body(
    unsigned char* lds, const float* __restrict__ X, int ldx,
    const float* __restrict__ W, int ldw, const float* __restrict__ bias,
    float* __restrict__ C, int ldc, unsigned char* __restrict__ maskOut,
    const unsigned char* __restrict__ maskMul, int K, int N, int mode)
{
    const int tid = threadIdx.x;
    const int m0 = blockIdx.x * 128;
    const int n0 = blockIdx.y * 64;
    float (*Xs)[132] = (float(*)[132])lds;                 // 16896 B
    float (*Ws)[68]  = (float(*)[68])(lds + 16896);        // 8704 B
    const int tx = tid & 15, ty = tid >> 4;                // ty 0..31
    float acc[4][4] = {};
    float4 xr[2], wr;

    DF_LOAD(0);
    DF_STASH();
    __syncthreads();

    for (int k0 = 0; k0 < K; k0 += 32) {
        bool last = (k0 + 32 >= K);
        if (!last) DF_LOAD(k0 + 32);
        #pragma unroll
        for (int kk = 0; kk < 32; ++kk) {
            float4 a0 = *(const float4*)&Xs[kk][ty * 4];
            float4 b0 = *(const float4*)&Ws[kk][tx * 4];
            float av[4] = {a0.x, a0.y, a0.z, a0.w};
            float bv[4] = {b0.x, b0.y, b0.z, b0.w};
            #pragma unroll
            for (int i = 0; i < 4; ++i)
                #pragma unroll
                for (int j = 0; j < 4; ++j)
                    acc[i][j] = fmaf(av[i], bv[j], acc[i][j]);
        }
        __syncthreads();
        if (!last) {
            DF_STASH();
            __syncthreads();
        }
    }

    float4 bb = {0, 0, 0, 0};
    if (mode & 1) bb = *(const float4*)(bias + n0 + tx * 4);
    const int c0 = n0 + tx * 4;
    #pragma unroll
    for (int i = 0; i < 4; ++i) {
        int r = m0 + ty * 4 + i;
        float v[4];
        #pragma unroll
        for (int j = 0; j < 4; ++j) {
            v[j] = acc[i][j];
            if (mode & 1) v[j] += ((const float*)&bb)[j];
        }
        if (mode & 8) {
            uchar4 mo;
            mo.x = v[0] > 0.0f; mo.y = v[1] > 0.0f; mo.z = v[2] > 0.0f; mo.w = v[3] > 0.0f;
            *(uchar4*)&maskOut[(size_t)r * N + c0] = mo;
        }
        if (mode & 16) {
            uchar4 mm = *(const uchar4*)&maskMul[(size_t)r * N + c0];
            v[0] *= mm.x; v[1] *= mm.y; v[2] *= mm.z; v[3] *= mm.w;
        }
        if (mode & 2) {
            #pragma unroll
            for (int j = 0; j < 4; ++j) v[j] = fmaxf(v[j], 0.0f);
        }
        if (mode & 4) {
            float4 st = {v[0], v[1], v[2], v[3]};
            *(float4*)(C + (size_t)r * ldc + c0) = st;
        }
    }
}
#undef DF_LOAD
#undef DF_STASH

#define DM_LOAD(k0)                                                                \
    {                                                                              \
        _Pragma("unroll")                                                          \
        for (int r = 0; r < 2; ++r) {                                              \
            int idx = tid + r * 512;                                               \
            int row = idx >> 3, kq = (idx & 7) * 4;                                \
            xr[r] = *(const float4*)(X + (size_t)(m0 + row) * ldx + (k0) + kq);    \
        }                                                                          \
        if (wload) {                                                               \
            int row = tid >> 2, kc = (tid & 3) * 8;                                \
            wh = *(const s8v*)(Whi + (size_t)(n0 + row) * ldw + (k0) + kc);        \
            wl = *(const s8v*)(Wlo + (size_t)(n0 + row) * ldw + (k0) + kc);        \
        }                                                                          \
    }
#define DM_STASH()                                                                 \
    {                                                                              \
        _Pragma("unroll")                                                          \
        for (int r = 0; r < 2; ++r) {                                              \
            int idx = tid + r * 512;                                               \
            int row = idx >> 3, kq = (idx & 7) * 4;                                \
            float a[4] = {xr[r].x, xr[r].y, xr[r].z, xr[r].w};                     \
            s4v hv, lv;                                                            \
            _Pragma("unroll")                                                      \
            for (int j = 0; j < 4; ++j) {                                          \
                unsigned short h = f2bf(a[j]);                                     \
                hv[j] = (short)h;                                                  \
                lv[j] = (short)f2bf(a[j] - bf2f(h));                               \
            }                                                                      \
            *(s4v*)&Xh[row * 40 + kq] = hv;                                        \
            *(s4v*)&Xl[row * 40 + kq] = lv;                                        \
        }                                                                          \
        if (wload) {                                                               \
            int row = tid >> 2, kc = (tid & 3) * 8;                                \
            *(s8v*)&Wsh[row * 40 + kc] = wh;                                       \
            *(s8v*)&Wsl[row * 40 + kc] = wl;                                       \
        }                                                                          \
    }

static __device__ __forceinline__ void dual_mfma_body(
    unsigned char* lds, const float* __restrict__ X, int ldx,
    const unsigned short* __restrict__ Whi, const unsigned short* __restrict__ Wlo, int ldw,
    const float* __restrict__ bias, float* __restrict__ C, int ldc,
    unsigned char* __restrict__ maskOut, const unsigned char* __restrict__ maskMul,
    int K, int N, int mode)
{
    const int tid = threadIdx.x;
    const int m0 = blockIdx.x * 128;
    const int n0 = blockIdx.y * 64;
    unsigned short* Xh  = (unsigned short*)lds;            // 128*40 = 10240 B
    unsigned short* Xl  = (unsigned short*)(lds + 10240);  // 10240 B
    unsigned short* Wsh = (unsigned short*)(lds + 20480);  // 5120 B
    unsigned short* Wsl = (unsigned short*)(lds + 25600);  // 5120 B

    const int wave = tid >> 6, lane = tid & 63;
    const int q = lane >> 4, ln = lane & 15;
    const int wm = (wave & 3) * 32;      // m-offset (0..96)
    const int wn = (wave >> 2) * 32;     // n-offset (0/32)

    f4v acc[2][2];
    #pragma unroll
    for (int mt = 0; mt < 2; ++mt)
        #pragma unroll
        for (int nt = 0; nt < 2; ++nt)
            acc[mt][nt] = (f4v)(0.0f);

    float4 xr[2];
    s8v wh, wl;
    const bool wload = (tid < 256);

    DM_LOAD(0);
    DM_STASH();
    __syncthreads();

    for (int k0 = 0; k0 < K; k0 += 32) {
        bool last = (k0 + 32 >= K);
        if (!last) DM_LOAD(k0 + 32);

        s8v ah[2], al[2], bh[2], bl[2];
        #pragma unroll
        for (int mt = 0; mt < 2; ++mt) {
            int rowm = wm + mt * 16 + ln;
            ah[mt] = *(const s8v*)&Xh[rowm * 40 + q * 8];
            al[mt] = *(const s8v*)&Xl[rowm * 40 + q * 8];
        }
        #pragma unroll
        for (int nt = 0; nt < 2; ++nt) {
            int rown = wn + nt * 16 + ln;
            bh[nt] = *(const s8v*)&Wsh[rown * 40 + q * 8];
            bl[nt] = *(const s8v*)&Wsl[rown * 40 + q * 8];
        }
        #pragma unroll
        for (int mt = 0; mt < 2; ++mt)
            #pragma unroll
            for (int nt = 0; nt < 2; ++nt) {
                acc[mt][nt] = __builtin_amdgcn_mfma_f32_16x16x32_bf16(ah[mt], bh[nt], acc[mt][nt], 0, 0, 0);
                acc[mt][nt] = __builtin_amdgcn_mfma_f32_16x16x32_bf16(ah[mt], bl[nt], acc[mt][nt], 0, 0, 0);
                acc[mt][nt] = __builtin_amdgcn_mfma_f32_16x16x32_bf16(al[mt], bh[nt], acc[mt][nt], 0, 0, 0);
            }

        __syncthreads();
        if (!last) {
            DM_STASH();
            __syncthreads();
        }
    }

    // epilogue: C-layout col=lane&15, row=q*4+r (m89-verified)
    #pragma unroll
    for (int nt = 0; nt < 2; ++nt) {
        int n = n0 + wn + nt * 16 + ln;
        float bv = (mode & 1) ? bias[n] : 0.0f;
        #pragma unroll
        for (int mt = 0; mt < 2; ++mt) {
            int mbase = m0 + wm + mt * 16 + q * 4;
            #pragma unroll
            for (int r = 0; r < 4; ++r) {
                int m = mbase + r;
                float v = acc[mt][nt][r] + bv;
                if (mode & 8)  maskOut[(size_t)m * N + n] = (v > 0.0f) ? 1 : 0;
                if (mode & 16) v *= (float)maskMul[(size_t)m * N + n];
                if (mode & 2)  v = fmaxf(v, 0.0f);
                if (mode & 4)  C[(size_t)m * ldc + n] = v;
            }
        }
    }
}
#undef DM_LOAD
#undef DM_STASH

// ======== mixed dual GEMM (R16): z=0 fp32 t-branch, z=1 split-bf16 MFMA z-branch ========
__global__ __launch_bounds__(512) void gemm_dualM(
    const float* __restrict__ X0, const float* __restrict__ X1, int ldx,
    const float* __restrict__ W, int ldw,
    const unsigned short* __restrict__ Whi, const unsigned short* __restrict__ Wlo,
    const float* __restrict__ bias,
    float* __restrict__ C0, float* __restrict__ C1, int ldc,
    unsigned char* __restrict__ mo0, unsigned char* __restrict__ mo1,
    int K, int N, int mode)
{
    __shared__ __align__(16) unsigned char lds[30720];
    if (blockIdx.z == 0)
        dual_fp32_body(lds, X0, ldx, W, ldw, bias, C0, ldc, mo0, 0, K, N, mode);
    else
        dual_mfma_body(lds, X1, ldx, Whi, Wlo, ldw, bias, C1, ldc, mo1, 0, K, N, mode);
}

// ======== fused dual4 (R16): z=0 t-h(next), z=1 z-h(next), z=2 t-delta(prev), z=3 z-delta ====
__global__ __launch_bounds__(512) void gemm_dual4(
    const float* __restrict__ X0, const float* __restrict__ X1, int ldx,
    const float* __restrict__ Wn, const float* __restrict__ Wd, int ldw,
    const unsigned short* __restrict__ WnH, const unsigned short* __restrict__ WnL,
    const unsigned short* __restrict__ WdH, const unsigned short* __restrict__ WdL,
    const float* __restrict__ bn, const float* __restrict__ bd,
    float* __restrict__ C0, float* __restrict__ C1, int ldc,
    unsigned char* __restrict__ mot, unsigned char* __restrict__ moz,
    int K, int N)
{
    __shared__ __align__(16) unsigned char lds[30720];
    int z = blockIdx.z;
    if (z == 0)
        dual_fp32_body(lds, X0, ldx, Wn, ldw, bn, C0, ldc, 0, 0, K, N, 1 | 2 | 4);
    else if (z == 2)
        dual_fp32_body(lds, X0, ldx, Wd, ldw, bd, 0, ldc, mot, 0, K, N, 1 | 8);
    else if (z == 1)
        dual_mfma_body(lds, X1, ldx, WnH, WnL, ldw, bn, C1, ldc, 0, 0, K, N, 1 | 2 | 4);
    else
        dual_mfma_body(lds, X1, ldx, WdH, WdL, ldw, bd, 0, ldc, moz, 0, K, N, 1 | 8);
}

// ======== single-plane MFMA GEMM (512-thr dual body) — V1,V2,V3 (mask-consuming) ========
__global__ __launch_bounds__(512) void gemm_m1(
    const float* __restrict__ X, int ldx,
    const unsigned short* __restrict__ Whi, const unsigned short* __restrict__ Wlo, int ldw,
    float* __restrict__ C, int ldc,
    const unsigned char* __restrict__ maskMul,
    int K, int N, int mode)
{
    __shared__ __align__(16) unsigned char lds[30720];
    dual_mfma_body(lds, X, ldx, Whi, Wlo, ldw, 0, C, ldc, 0, maskMul, K, N, mode);
}

// ======== all-MFMA 2-plane — fused finals (h_out output-only, h_dot mask-consuming) ========
__global__ __launch_bounds__(512) void gemm_mm(
    const float* __restrict__ X0, const float* __restrict__ X1, int ldx,
    const unsigned short* __restrict__ Whi, const unsigned short* __restrict__ Wlo, int ldw,
    const float* __restrict__ bias,
    float* __restrict__ C0, float* __restrict__ C1, int ldc,
    int K, int N, int mode0, int mode1)
{
    __shared__ __align__(16) unsigned char lds[30720];
    if (blockIdx.z == 0)
        dual_mfma_body(lds, X0, ldx, Whi, Wlo, ldw, bias, C0, ldc, 0, 0, K, N, mode0);
    else
        dual_mfma_body(lds, X1, ldx, Whi, Wlo, ldw, bias, C1, ldc, 0, 0, K, N, mode1);
}

// ---------- zng: bf16 MFMA Jacobian chain (R16-validated, byte-identical) ----------
__global__ __launch_bounds__(512, 4) void zng_kernel(
    const unsigned short* __restrict__ WhF,    // [2][16][32][64][8] frag-packed Wh1,Wh2
    const unsigned short* __restrict__ WoF,    // [2][32][64][8] frag-packed Wout
    const unsigned short* __restrict__ G0F,    // [32][2][64][8] frag-packed G0
    const unsigned char* __restrict__ mz1,
    const unsigned char* __restrict__ mz2,
    const unsigned char* __restrict__ mz3,
    float* __restrict__ out)                   // (4096,192), writes cols 128..191
{
    __shared__ __align__(16) unsigned short RtF[32 * 2 * 64 * 8]; // 65536 B, fragment order
    __shared__ unsigned char m2s[512];
    __shared__ unsigned char m3s[512];

    const int b0  = blockIdx.x;     // one batch element per block
    const int tid = threadIdx.x;

    m2s[tid] = mz2[(size_t)b0 * 512 + tid];
    m3s[tid] = mz3[(size_t)b0 * 512 + tid];

    // ---- setup: RtF = frag(mask1 (.) G0^T); coalesced read + linear LDS write ----
    #pragma unroll
    for (int it = 0; it < 8; ++it) {
        int sl = it * 512 + tid;           // fragment slot 0..4095
        int ls = sl & 63;                  // lane within fragment
        int ks = sl >> 7;                  // k-step
        int k0 = ks * 16 + (ls >> 5) * 8;  // first k of this lane's 8 elems
        s8v g = *(const s8v*)(G0F + (size_t)sl * 8);
        const unsigned char* mm = mz1 + (size_t)b0 * 512 + k0;
        unsigned int mlo = *(const unsigned int*)(mm);
        unsigned int mhi = *(const unsigned int*)(mm + 4);
        s8v r;
        #pragma unroll
        for (int j = 0; j < 4; ++j) r[j] = ((mlo >> (8 * j)) & 1) ? g[j] : (short)0;
        #pragma unroll
        for (int j = 0; j < 4; ++j) r[4 + j] = ((mhi >> (8 * j)) & 1) ? g[4 + j] : (short)0;
        *(s8v*)(&RtF[(size_t)sl * 8]) = r;
    }
    __syncthreads();

    const int lane = tid & 63, wave = tid >> 6;
    const int l31 = lane & 31, h = lane >> 5;

    // ---- 2 chained layers: R <- mask (.) (Wh @ R) ----
    for (int s = 0; s < 2; ++s) {
        const unsigned short* Ar0 = WhF + (size_t)s * 262144
                                  + (size_t)(wave * 2) * 16384 + lane * 8;
        const unsigned short* Ar1 = Ar0 + 16384;

        f16v acc[2][2];
        #pragma unroll
        for (int mt = 0; mt < 2; ++mt)
            #pragma unroll
            for (int nt = 0; nt < 2; ++nt)
                acc[mt][nt] = (f16v)(0.0f);

        // 2-deep A prefetch (L2 ~200cyc), 1-deep B prefetch (LDS)
        s8v a0A = *(const s8v*)(Ar0);
        s8v a1A = *(const s8v*)(Ar1);
        s8v a0B = *(const s8v*)(Ar0 + 512);
        s8v a1B = *(const s8v*)(Ar1 + 512);
        s8v b0c = *(const s8v*)&RtF[lane * 8];
        s8v b1c = *(const s8v*)&RtF[512 + lane * 8];

        #pragma unroll 4
        for (int ks = 0; ks < 32; ++ks) {
            int kf = ((ks + 2) & 31) * 512;           // A: wraps; redundant tail loads
            s8v a0N = *(const s8v*)(Ar0 + kf);
            s8v a1N = *(const s8v*)(Ar1 + kf);
            int kb = ((ks + 1) & 31) * 1024;          // B: fragment-linear
            s8v b0n = *(const s8v*)&RtF[kb + lane * 8];
            s8v b1n = *(const s8v*)&RtF[kb + 512 + lane * 8];

            __builtin_amdgcn_s_setprio(1);
            acc[0][0] = __builtin_amdgcn_mfma_f32_32x32x16_bf16(a0A, b0c, acc[0][0], 0, 0, 0);
            acc[0][1] = __builtin_amdgcn_mfma_f32_32x32x16_bf16(a0A, b1c, acc[0][1], 0, 0, 0);
            acc[1][0] = __builtin_amdgcn_mfma_f32_32x32x16_bf16(a1A, b0c, acc[1][0], 0, 0, 0);
            acc[1][1] = __builtin_amdgcn_mfma_f32_32x32x16_bf16(a1A, b1c, acc[1][1], 0, 0, 0);
            __builtin_amdgcn_s_setprio(0);

            a0A = a0B; a0B = a0N;
            a1A = a1B; a1B = a1N;
            b0c = b0n; b1c = b1n;
        }
        __syncthreads();

        // ---- epilogue: mask, pack bf16, write new RtF (fragment order, conflict-free) ----
        const unsigned char* msk = (s == 0) ? m2s : m3s;
        #pragma unroll
        for (int mt = 0; mt < 2; ++mt) {
            #pragma unroll
            for (int g = 0; g < 4; ++g) {
                int kk = wave * 64 + mt * 32 + g * 8 + h * 4;   // output k-row base
                int ks = wave * 4 + mt * 2 + (g >> 1);
                int khalf = g & 1;
                uchar4 mv = *(const uchar4*)&msk[kk];
                unsigned char mb[4] = {mv.x, mv.y, mv.z, mv.w};
                #pragma unroll
                for (int nt = 0; nt < 2; ++nt) {
                    s4v pk;
                    #pragma unroll
                    for (int r = 0; r < 4; ++r) {
                        float v = mb[r] ? acc[mt][nt][g * 4 + r] : 0.0f;
                        pk[r] = (short)f2bf(v);
                    }
                    *(s4v*)(&RtF[(ks * 2 + nt) * 512 + (l31 + 32 * khalf) * 8 + h * 4]) = pk;
                }
            }
        }
        __syncthreads();
    }

    // ---- final: Wout @ R, row norms; waves 0-1 only (no barriers below) ----
    if (wave < 2) {
        const unsigned short* Wr = WoF + wave * 16384 + lane * 8;
        f16v a3[2];
        a3[0] = (f16v)(0.0f);
        a3[1] = (f16v)(0.0f);
        #pragma unroll 2
        for (int ks = 0; ks < 32; ++ks) {
            s8v af = *(const s8v*)(Wr + ks * 512);
            s8v bb0 = *(const s8v*)&RtF[ks * 1024 + lane * 8];
            s8v bb1 = *(const s8v*)&RtF[ks * 1024 + 512 + lane * 8];
            a3[0] = __builtin_amdgcn_mfma_f32_32x32x16_bf16(af, bb0, a3[0], 0, 0, 0);
            a3[1] = __builtin_amdgcn_mfma_f32_32x32x16_bf16(af, bb1, a3[1], 0, 0, 0);
        }
        // per-lane: rows wave*32 + g*8 + h*4 + r, cols (nt*32 + l31)
        float sq[16];
        #pragma unroll
        for (int i = 0; i < 16; ++i) {
            float v0 = a3[0][i], v1 = a3[1][i];
            sq[i] = fmaf(v0, v0, v1 * v1);
        }
        #pragma unroll
        for (int off = 1; off < 32; off <<= 1)
            #pragma unroll
            for (int i = 0; i < 16; ++i)
                sq[i] += __shfl_xor(sq[i], off, 64);
        if (l31 == 0) {
            #pragma unroll
            for (int g = 0; g < 4; ++g)
                #pragma unroll
                for (int r = 0; r < 4; ++r)
                    out[(size_t)b0 * 192 + 128 + wave * 32 + g * 8 + h * 4 + r] = sqrtf(sq[g * 4 + r]);
        }
    }
}

// ---------- host ----------
extern "C" void kernel_launch(void* const* d_in, const int* in_sizes, int n_in,
                              void* d_out, int out_size, void* d_ws, size_t ws_size,
                              hipStream_t stream) {
    const float* x    = (const float*)d_in[0];
    const float* Win  = (const float*)d_in[1];
    const float* bin  = (const float*)d_in[2];
    const float* Wh   = (const float*)d_in[3];
    const float* bh   = (const float*)d_in[4];
    const float* Wout = (const float*)d_in[5];
    const float* bout = (const float*)d_in[6];
    float* out = (float*)d_out;

    char* ws = (char*)d_ws;
    unsigned short* whi  = (unsigned short*)(ws);                   // 1703936 B
    unsigned short* wlo  = (unsigned short*)(ws + 1703936);         // 1703936 B
    unsigned short* G0hi = (unsigned short*)(ws + 3407872);         // 65536 B
    unsigned short* G0lo = (unsigned short*)(ws + 3473408);         // 65536 B
    unsigned short* G0F  = (unsigned short*)(ws + 3538944);         // 65536 B (frag-packed)
    unsigned char*  masks = (unsigned char*)(ws + 3604480);         // 6 * 2 MB
    unsigned char* mt1 = masks + 0 * 2097152;
    unsigned char* mt2 = masks + 1 * 2097152;
    unsigned char* mt3 = masks + 2 * 2097152;
    unsigned char* mz1 = masks + 3 * 2097152;
    unsigned char* mz2 = masks + 4 * 2097152;
    unsigned char* mz3 = masks + 5 * 2097152;
    float* bufs = (float*)(ws + 3604480 + 12582912);                // 4 x 8 MB
    float* tA = bufs + 0 * 2097152;
    float* tB = bufs + 1 * 2097152;
    float* zA = bufs + 2 * 2097152;
    float* zB = bufs + 3 * 2097152;
    unsigned short* WhF = (unsigned short*)(ws + 49741824);         // 1048576 B
    unsigned short* WoF = (unsigned short*)(ws + 50790400);         // 65536 B

    // hi/lo plane offsets (elems): [Win@0 | Wh0@32768 | Wh1@294912 | Wh2@557056 | Wout@819200]
    const unsigned short* WinH  = whi,          *WinL  = wlo;
    const unsigned short* Wh0H  = whi + 32768,  *Wh0L  = wlo + 32768;
    const unsigned short* Wh1H  = whi + 294912, *Wh1L  = wlo + 294912;
    const unsigned short* Wh2H  = whi + 557056, *Wh2L  = wlo + 557056;
    const unsigned short* WoutH = whi + 819200, *WoutL = wlo + 819200;

    const float* Wh0 = Wh;
    const float* Wh1 = Wh + 262144;
    const float* Wh2 = Wh + 524288;
    const float* bh0 = bh, *bh1 = bh + 512, *bh2 = bh + 1024;

    conv_split<<<dim3(3328), dim3(256), 0, stream>>>(Win, Wh, Wout, whi, wlo);
    frag_pack<<<dim3(273), dim3(256), 0, stream>>>(whi, WhF, WoF);
    g0_kernel<<<dim3(512), dim3(64), 0, stream>>>(Wh0, Win, G0hi, G0lo, G0F);

    auto gdual = [&](const float* X0, const float* X1, int ldx,
                     const float* W, const unsigned short* WH, const unsigned short* WL, int ldw,
                     const float* bias, float* C0, float* C1, int ldc,
                     unsigned char* mo0, unsigned char* mo1,
                     int K, int N, int mode) {
        dim3 g(4096 / 128, N / 64, 2);
        gemm_dualM<<<g, dim3(512), 0, stream>>>(X0, X1, ldx, W, ldw, WH, WL, bias,
                                                C0, C1, ldc, mo0, mo1, K, N, mode);
    };
    auto gdual4 = [&](const float* X0, const float* X1,
                      const float* Wn, const unsigned short* WnH, const unsigned short* WnL,
                      const float* Wd, const unsigned short* WdH, const unsigned short* WdL,
                      const float* bn, const float* bd,
                      float* C0, float* C1,
                      unsigned char* mot, unsigned char* moz) {
        dim3 g(4096 / 128, 8, 4);
        gemm_dual4<<<g, dim3(512), 0, stream>>>(X0, X1, 512, Wn, Wd, 512, WnH, WnL, WdH, WdL,
                                                bn, bd, C0, C1, 512, mot, moz, 512, 512);
    };
    auto gm1 = [&](const float* X, int ldx,
                   const unsigned short* WH, const unsigned short* WL, int ldw,
                   float* C, int ldc, const unsigned char* mm, int K, int N, int mode) {
        dim3 g(4096 / 128, N / 64, 1);
        gemm_m1<<<g, dim3(512), 0, stream>>>(X, ldx, WH, WL, ldw, C, ldc, mm, K, N, mode);
    };

    // ---- fused forward + delta chain (t fp32 for mask fidelity; z split-bf16 MFMA) ----
    gdual(x, x + 128, 192, Win, WinH, WinL, 64, bin, tA, zA, 512, 0, 0, 64, 512, 1 | 4);              // h0
    gdual(tA, zA, 512, Wh0, Wh0H, Wh0L, 512, bh0, tB, zB, 512, 0, 0, 512, 512, 1 | 2 | 4);            // h1
    gdual4(tB, zB, Wh1, Wh1H, Wh1L, Wh0, Wh0H, Wh0L, bh1, bh0, tA, zA, mt1, mz1);                     // h2 + delta1
    gdual4(tA, zA, Wh2, Wh2H, Wh2L, Wh1, Wh1H, Wh1L, bh2, bh1, tB, zB, mt2, mz2);                     // h3 + delta2
    gdual(tB, zB, 512, Wh2, Wh2H, Wh2L, 512, bh2, 0, 0, 0, mt3, mz3, 512, 512, 1 | 8);                // delta3

    // ---- zng (z-branch Jacobian row norms), 1 elem/block, 2 blocks/CU ----
    zng_kernel<<<dim3(4096), dim3(512), 0, stream>>>(WhF, WoF, G0F, mz1, mz2, mz3, out);

    // ---- h_dot chain: V = D (.) (W v)  (mask-consuming -> split-bf16 MFMA safe) ----
    gm1(x + 64, 192, G0hi, G0lo, 64, tA, 512, mt1, 64, 512, 4 | 16);                                  // V1
    gm1(tA, 512, Wh1H, Wh1L, 512, zA, 512, mt2, 512, 512, 4 | 16);                                    // V2
    gm1(zA, 512, Wh2H, Wh2L, 512, zB, 512, mt3, 512, 512, 4 | 16);                                    // V3

    // ---- fused finals: h_out (t, cols 0..63, +bias, output-only) + h_dot (V3, cols 64..127) ----
    gemm_mm<<<dim3(32, 1, 2), dim3(512), 0, stream>>>(tB, zB, 512, WoutH, WoutL, 512, bout,
                                                      out, out + 64, 192, 512, 64, 1 | 4, 4);
}

// Round 6
// 661.984 us; speedup vs baseline: 1.5304x; 1.0116x over previous
//
#include <hip/hip_runtime.h>
#include <math.h>

typedef __attribute__((ext_vector_type(8))) short s8v;   // 8 x bf16
typedef __attribute__((ext_vector_type(4))) short s4v;   // 4 x bf16
typedef __attribute__((ext_vector_type(4))) float f4v;   // 4 x f32
typedef __attribute__((ext_vector_type(16))) float f16v; // 16 x f32

static __device__ __forceinline__ unsigned short f2bf(float f) {
    union { float f; unsigned int u; } v; v.f = f;
    unsigned int r = v.u + 0x7fffu + ((v.u >> 16) & 1u);   // RNE
    return (unsigned short)(r >> 16);
}
static __device__ __forceinline__ float bf2f(unsigned short h) {
    union { unsigned int u; float f; } t; t.u = ((unsigned int)h) << 16;
    return t.f;
}

// ---------- fused: weight hi/lo split + G0 = Wh0 @ W_in ----------
// blocks 0..3327: split [Win(32768) | Wh(786432) | Wout(32768)] to bf16 hi/lo planes
// blocks 3328..3455: G0 rows (4 rows/block, 64 threads/row) + fragment-packed G0F
__global__ void conv_g0(const float* __restrict__ Win, const float* __restrict__ Wh,
                        const float* __restrict__ Wout,
                        unsigned short* __restrict__ whi, unsigned short* __restrict__ wlo,
                        unsigned short* __restrict__ G0hi, unsigned short* __restrict__ G0lo,
                        unsigned short* __restrict__ G0F) {
    if (blockIdx.x < 3328) {
        int i = blockIdx.x * 256 + threadIdx.x;
        float v;
        if (i < 32768)       v = Win[i];
        else if (i < 819200) v = Wh[i - 32768];
        else                 v = Wout[i - 819200];
        unsigned short h = f2bf(v);
        whi[i] = h;
        wlo[i] = f2bf(v - bf2f(h));
    } else {
        int i = (blockIdx.x - 3328) * 4 + (threadIdx.x >> 6);   // 0..511 (hidden)
        int j = threadIdx.x & 63;                               // 0..63  (d)
        float acc = 0.f;
        for (int k = 0; k < 512; ++k)
            acc = fmaf(Wh[i * 512 + k], Win[k * 64 + j], acc);
        unsigned short h = f2bf(acc);
        G0hi[i * 64 + j] = h;
        G0lo[i * 64 + j] = f2bf(acc - bf2f(h));
        int sl = ((i >> 4) * 2 + (j >> 5)) * 64 + (j & 31) + 32 * ((i >> 3) & 1);
        G0F[(size_t)sl * 8 + (i & 7)] = h;
    }
}

// ================= shared GEMM bodies (R18-validated; m0/n0 now parameters) =================
// fp32 body: mask-PRODUCING chain must stay fp32 (R17 lesson: 3-term bf16 preact
// error ~2e-4 flips ~900 masks -> h_dot absmax 0.14).

#define DF_LOAD(k0)                                                              \
    {                                                                            \
        _Pragma("unroll")                                                        \
        for (int r = 0; r < 2; ++r) {                                            \
            int idx = tid + r * 512;                                             \
            int row = idx >> 3, kq = (idx & 7) * 4;                              \
            xr[r] = *(const float4*)(X + (size_t)(m0 + row) * ldx + (k0) + kq);  \
        }                                                                        \
        {                                                                        \
            int row = tid >> 3, kq = (tid & 7) * 4;                              \
            wr = *(const float4*)(W + (size_t)(n0 + row) * ldw + (k0) + kq);     \
        }                                                                        \
    }
#define DF_STASH()                                                               \
    {                                                                            \
        _Pragma("unroll")                                                        \
        for (int r = 0; r < 2; ++r) {                                            \
            int idx = tid + r * 512;                                             \
            int row = idx >> 3, kq = (idx & 7) * 4;                              \
            Xs[kq + 0][row] = xr[r].x; Xs[kq + 1][row] = xr[r].y;                \
            Xs[kq + 2][row] = xr[r].z; Xs[kq + 3][row] = xr[r].w;                \
        }                                                                        \
        {                                                                        \
            int row = tid >> 3, kq = (tid & 7) * 4;                              \
            Ws[kq + 0][row] = wr.x; Ws[kq + 1][row] = wr.y;                      \
            Ws[kq + 2][row] = wr.z; Ws[kq + 3][row] = wr.w;                      \
        }                                                                        \
    }

static __device__ __forceinline__ void dual_fp32_body(
    unsigned char* lds, const float* __restrict__ X, int ldx,
    const float* __restrict__ W, int ldw, const float* __restrict__ bias,
    float* __restrict__ C, int ldc, unsigned char* __restrict__ maskOut,
    const unsigned char* __restrict__ maskMul, int K, int N, int mode,
    int m0, int n0)
{
    const int tid = threadIdx.x;
    float (*Xs)[132] = (float(*)[132])lds;                 // 16896 B
    float (*Ws)[68]  = (float(*)[68])(lds + 16896);        // 8704 B
    const int tx = tid & 15, ty = tid >> 4;                // ty 0..31
    float acc[4][4] = {};
    float4 xr[2], wr;

    DF_LOAD(0);
    DF_STASH();
    __syncthreads();

    for (int k0 = 0; k0 < K; k0 += 32) {
        bool last = (k0 + 32 >= K);
        if (!last) DF_LOAD(k0 + 32);
        #pragma unroll
        for (int kk = 0; kk < 32; ++kk) {
            float4 a0 = *(const float4*)&Xs[kk][ty * 4];
            float4 b0 = *(const float4*)&Ws[kk][tx * 4];
            float av[4] = {a0.x, a0.y, a0.z, a0.w};
            float bv[4] = {b0.x, b0.y, b0.z, b0.w};
            #pragma unroll
            for (int i = 0; i < 4; ++i)
                #pragma unroll
                for (int j = 0; j < 4; ++j)
                    acc[i][j] = fmaf(av[i], bv[j], acc[i][j]);
        }
        __syncthreads();
        if (!last) {
            DF_STASH();
            __syncthreads();
        }
    }

    float4 bb = {0, 0, 0, 0};
    if (mode & 1) bb = *(const float4*)(bias + n0 + tx * 4);
    const int c0 = n0 + tx * 4;
    #pragma unroll
    for (int i = 0; i < 4; ++i) {
        int r = m0 + ty * 4 + i;
        float v[4];
        #pragma unroll
        for (int j = 0; j < 4; ++j) {
            v[j] = acc[i][j];
            if (mode & 1) v[j] += ((const float*)&bb)[j];
        }
        if (mode & 8) {
            uchar4 mo;
            mo.x = v[0] > 0.0f; mo.y = v[1] > 0.0f; mo.z = v[2] > 0.0f; mo.w = v[3] > 0.0f;
            *(uchar4*)&maskOut[(size_t)r * N + c0] = mo;
        }
        if (mode & 16) {
            uchar4 mm = *(const uchar4*)&maskMul[(size_t)r * N + c0];
            v[0] *= mm.x; v[1] *= mm.y; v[2] *= mm.z; v[3] *= mm.w;
        }
        if (mode & 2) {
            #pragma unroll
            for (int j = 0; j < 4; ++j) v[j] = fmaxf(v[j], 0.0f);
        }
        if (mode & 4) {
            float4 st = {v[0], v[1], v[2], v[3]};
            *(float4*)(C + (size_t)r * ldc + c0) = st;
        }
    }
}
#undef DF_LOAD
#undef DF_STASH

#define DM_LOAD(k0)                                                                \
    {                                                                              \
        _Pragma("unroll")                                                          \
        for (int r = 0; r < 2; ++r) {                                              \
            int idx = tid + r * 512;                                               \
            int row = idx >> 3, kq = (idx & 7) * 4;                                \
            xr[r] = *(const float4*)(X + (size_t)(m0 + row) * ldx + (k0) + kq);    \
        }                                                                          \
        if (wload) {                                                               \
            int row = tid >> 2, kc = (tid & 3) * 8;                                \
            wh = *(const s8v*)(Whi + (size_t)(n0 + row) * ldw + (k0) + kc);        \
            wl = *(const s8v*)(Wlo + (size_t)(n0 + row) * ldw + (k0) + kc);        \
        }                                                                          \
    }
#define DM_STASH()                                                                 \
    {                                                                              \
        _Pragma("unroll")                                                          \
        for (int r = 0; r < 2; ++r) {                                              \
            int idx = tid + r * 512;                                               \
            int row = idx >> 3, kq = (idx & 7) * 4;                                \
            float a[4] = {xr[r].x, xr[r].y, xr[r].z, xr[r].w};                     \
            s4v hv, lv;                                                            \
            _Pragma("unroll")                                                      \
            for (int j = 0; j < 4; ++j) {                                          \
                unsigned short h = f2bf(a[j]);                                     \
                hv[j] = (short)h;                                                  \
                lv[j] = (short)f2bf(a[j] - bf2f(h));                               \
            }                                                                      \
            *(s4v*)&Xh[row * 40 + kq] = hv;                                        \
            *(s4v*)&Xl[row * 40 + kq] = lv;                                        \
        }                                                                          \
        if (wload) {                                                               \
            int row = tid >> 2, kc = (tid & 3) * 8;                                \
            *(s8v*)&Wsh[row * 40 + kc] = wh;                                       \
            *(s8v*)&Wsl[row * 40 + kc] = wl;                                       \
        }                                                                          \
    }

static __device__ __forceinline__ void dual_mfma_body(
    unsigned char* lds, const float* __restrict__ X, int ldx,
    const unsigned short* __restrict__ Whi, const unsigned short* __restrict__ Wlo, int ldw,
    const float* __restrict__ bias, float* __restrict__ C, int ldc,
    unsigned char* __restrict__ maskOut, const unsigned char* __restrict__ maskMul,
    int K, int N, int mode, int m0, int n0)
{
    const int tid = threadIdx.x;
    unsigned short* Xh  = (unsigned short*)lds;            // 128*40 = 10240 B
    unsigned short* Xl  = (unsigned short*)(lds + 10240);  // 10240 B
    unsigned short* Wsh = (unsigned short*)(lds + 20480);  // 5120 B
    unsigned short* Wsl = (unsigned short*)(lds + 25600);  // 5120 B

    const int wave = tid >> 6, lane = tid & 63;
    const int q = lane >> 4, ln = lane & 15;
    const int wm = (wave & 3) * 32;      // m-offset (0..96)
    const int wn = (wave >> 2) * 32;     // n-offset (0/32)

    f4v acc[2][2];
    #pragma unroll
    for (int mt = 0; mt < 2; ++mt)
        #pragma unroll
        for (int nt = 0; nt < 2; ++nt)
            acc[mt][nt] = (f4v)(0.0f);

    float4 xr[2];
    s8v wh, wl;
    const bool wload = (tid < 256);

    DM_LOAD(0);
    DM_STASH();
    __syncthreads();

    for (int k0 = 0; k0 < K; k0 += 32) {
        bool last = (k0 + 32 >= K);
        if (!last) DM_LOAD(k0 + 32);

        s8v ah[2], al[2], bh[2], bl[2];
        #pragma unroll
        for (int mt = 0; mt < 2; ++mt) {
            int rowm = wm + mt * 16 + ln;
            ah[mt] = *(const s8v*)&Xh[rowm * 40 + q * 8];
            al[mt] = *(const s8v*)&Xl[rowm * 40 + q * 8];
        }
        #pragma unroll
        for (int nt = 0; nt < 2; ++nt) {
            int rown = wn + nt * 16 + ln;
            bh[nt] = *(const s8v*)&Wsh[rown * 40 + q * 8];
            bl[nt] = *(const s8v*)&Wsl[rown * 40 + q * 8];
        }
        #pragma unroll
        for (int mt = 0; mt < 2; ++mt)
            #pragma unroll
            for (int nt = 0; nt < 2; ++nt) {
                acc[mt][nt] = __builtin_amdgcn_mfma_f32_16x16x32_bf16(ah[mt], bh[nt], acc[mt][nt], 0, 0, 0);
                acc[mt][nt] = __builtin_amdgcn_mfma_f32_16x16x32_bf16(ah[mt], bl[nt], acc[mt][nt], 0, 0, 0);
                acc[mt][nt] = __builtin_amdgcn_mfma_f32_16x16x32_bf16(al[mt], bh[nt], acc[mt][nt], 0, 0, 0);
            }

        __syncthreads();
        if (!last) {
            DM_STASH();
            __syncthreads();
        }
    }

    // epilogue: C-layout col=lane&15, row=q*4+r (m89-verified)
    #pragma unroll
    for (int nt = 0; nt < 2; ++nt) {
        int n = n0 + wn + nt * 16 + ln;
        float bv = (mode & 1) ? bias[n] : 0.0f;
        #pragma unroll
        for (int mt = 0; mt < 2; ++mt) {
            int mbase = m0 + wm + mt * 16 + q * 4;
            #pragma unroll
            for (int r = 0; r < 4; ++r) {
                int m = mbase + r;
                float v = acc[mt][nt][r] + bv;
                if (mode & 8)  maskOut[(size_t)m * N + n] = (v > 0.0f) ? 1 : 0;
                if (mode & 16) v *= (float)maskMul[(size_t)m * N + n];
                if (mode & 2)  v = fmaxf(v, 0.0f);
                if (mode & 4)  C[(size_t)m * ldc + n] = v;
            }
        }
    }
}
#undef DM_LOAD
#undef DM_STASH

// ======== fused h0 + frag_pack: z=0 t-h0 fp32, z=1 z-h0 MFMA, z=2 frag_pack ========
__global__ __launch_bounds__(512) void h0_pack(
    const float* __restrict__ x, const float* __restrict__ Win,
    const unsigned short* __restrict__ WinH, const unsigned short* __restrict__ WinL,
    const float* __restrict__ bin, float* __restrict__ tA, float* __restrict__ zA,
    const unsigned short* __restrict__ whi,
    unsigned short* __restrict__ WhF, unsigned short* __restrict__ WoF)
{
    __shared__ __align__(16) unsigned char lds[30720];
    const int m0 = blockIdx.x * 128, n0 = blockIdx.y * 64;
    int z = blockIdx.z;
    if (z == 0)
        dual_fp32_body(lds, x, 192, Win, 64, bin, tA, 512, 0, 0, 64, 512, 1 | 4, m0, n0);
    else if (z == 1)
        dual_mfma_body(lds, x + 128, 192, WinH, WinL, 64, bin, zA, 512, 0, 0, 64, 512, 1 | 4, m0, n0);
    else {
        int i = (blockIdx.y * 32 + blockIdx.x) * 512 + threadIdx.x;   // s8v slot
        if (i < 65536) {
            int lane = i & 63, ks = (i >> 6) & 31, g32 = (i >> 11) & 15, s = i >> 15;
            int row = g32 * 32 + (lane & 31);
            int k   = ks * 16 + (lane >> 5) * 8;
            const unsigned short* src = whi + 294912 + (size_t)s * 262144 + row * 512 + k;
            *(s8v*)(WhF + (size_t)i * 8) = *(const s8v*)src;
        } else if (i < 65536 + 4096) {
            int j = i - 65536;
            int lane = j & 63, ks = (j >> 6) & 31, g32 = j >> 11;
            int row = g32 * 32 + (lane & 31);
            int k   = ks * 16 + (lane >> 5) * 8;
            const unsigned short* src = whi + 819200 + row * 512 + k;
            *(s8v*)(WoF + (size_t)j * 8) = *(const s8v*)src;
        }
    }
}

// ======== mixed dual GEMM (h1): z=0 fp32 t-branch, z=1 split-bf16 MFMA z-branch ========
__global__ __launch_bounds__(512) void gemm_dualM(
    const float* __restrict__ X0, const float* __restrict__ X1, int ldx,
    const float* __restrict__ W, int ldw,
    const unsigned short* __restrict__ Whi, const unsigned short* __restrict__ Wlo,
    const float* __restrict__ bias,
    float* __restrict__ C0, float* __restrict__ C1, int ldc,
    unsigned char* __restrict__ mo0, unsigned char* __restrict__ mo1,
    int K, int N, int mode)
{
    __shared__ __align__(16) unsigned char lds[30720];
    const int m0 = blockIdx.x * 128, n0 = blockIdx.y * 64;
    if (blockIdx.z == 0)
        dual_fp32_body(lds, X0, ldx, W, ldw, bias, C0, ldc, mo0, 0, K, N, mode, m0, n0);
    else
        dual_mfma_body(lds, X1, ldx, Whi, Wlo, ldw, bias, C1, ldc, mo1, 0, K, N, mode, m0, n0);
}

// ======== fused dual4: z=0 t-h(next), z=1 z-h(next), z=2 t-delta(prev), z=3 z-delta ====
__global__ __launch_bounds__(512) void gemm_dual4(
    const float* __restrict__ X0, const float* __restrict__ X1, int ldx,
    const float* __restrict__ Wn, const float* __restrict__ Wd, int ldw,
    const unsigned short* __restrict__ WnH, const unsigned short* __restrict__ WnL,
    const unsigned short* __restrict__ WdH, const unsigned short* __restrict__ WdL,
    const float* __restrict__ bn, const float* __restrict__ bd,
    float* __restrict__ C0, float* __restrict__ C1, int ldc,
    unsigned char* __restrict__ mot, unsigned char* __restrict__ moz,
    int K, int N)
{
    __shared__ __align__(16) unsigned char lds[30720];
    const int m0 = blockIdx.x * 128, n0 = blockIdx.y * 64;
    int z = blockIdx.z;
    if (z == 0)
        dual_fp32_body(lds, X0, ldx, Wn, ldw, bn, C0, ldc, 0, 0, K, N, 1 | 2 | 4, m0, n0);
    else if (z == 2)
        dual_fp32_body(lds, X0, ldx, Wd, ldw, bd, 0, ldc, mot, 0, K, N, 1 | 8, m0, n0);
    else if (z == 1)
        dual_mfma_body(lds, X1, ldx, WnH, WnL, ldw, bn, C1, ldc, 0, 0, K, N, 1 | 2 | 4, m0, n0);
    else
        dual_mfma_body(lds, X1, ldx, WdH, WdL, ldw, bd, 0, ldc, moz, 0, K, N, 1 | 8, m0, n0);
}

// ======== fused delta3 + V1: z=0 t-delta3 fp32, z=1 z-delta3 MFMA, z=2 V1 MFMA ========
// V1 = mask1 (.) (xdot @ G0^T): mt1 ready (d4#1, two dispatches earlier); writes tA (dead).
__global__ __launch_bounds__(512) void d3v1(
    const float* __restrict__ tB, const float* __restrict__ zB, const float* __restrict__ x,
    const float* __restrict__ Wh2,
    const unsigned short* __restrict__ Wh2H, const unsigned short* __restrict__ Wh2L,
    const unsigned short* __restrict__ G0hi, const unsigned short* __restrict__ G0lo,
    const float* __restrict__ bh2, float* __restrict__ tA,
    unsigned char* __restrict__ mt3, unsigned char* __restrict__ mz3,
    const unsigned char* __restrict__ mt1)
{
    __shared__ __align__(16) unsigned char lds[30720];
    const int m0 = blockIdx.x * 128, n0 = blockIdx.y * 64;
    int z = blockIdx.z;
    if (z == 0)
        dual_fp32_body(lds, tB, 512, Wh2, 512, bh2, 0, 512, mt3, 0, 512, 512, 1 | 8, m0, n0);
    else if (z == 1)
        dual_mfma_body(lds, zB, 512, Wh2H, Wh2L, 512, bh2, 0, 512, mz3, 0, 512, 512, 1 | 8, m0, n0);
    else
        dual_mfma_body(lds, x + 64, 192, G0hi, G0lo, 64, 0, tA, 512, 0, mt1, 64, 512, 4 | 16, m0, n0);
}

// ======== single-plane MFMA GEMM — V3 (mask-consuming) ========
__global__ __launch_bounds__(512) void gemm_m1(
    const float* __restrict__ X, int ldx,
    const unsigned short* __restrict__ Whi, const unsigned short* __restrict__ Wlo, int ldw,
    float* __restrict__ C, int ldc,
    const unsigned char* __restrict__ maskMul,
    int K, int N, int mode)
{
    __shared__ __align__(16) unsigned char lds[30720];
    dual_mfma_body(lds, X, ldx, Whi, Wlo, ldw, 0, C, ldc, 0, maskMul, K, N, mode,
                   blockIdx.x * 128, blockIdx.y * 64);
}

// ======== all-MFMA 2-plane — fused finals (h_out output-only, h_dot mask-consuming) ========
__global__ __launch_bounds__(512) void gemm_mm(
    const float* __restrict__ X0, const float* __restrict__ X1, int ldx,
    const unsigned short* __restrict__ Whi, const unsigned short* __restrict__ Wlo, int ldw,
    const float* __restrict__ bias,
    float* __restrict__ C0, float* __restrict__ C1, int ldc,
    int K, int N, int mode0, int mode1)
{
    __shared__ __align__(16) unsigned char lds[30720];
    const int m0 = blockIdx.x * 128, n0 = blockIdx.y * 64;
    if (blockIdx.z == 0)
        dual_mfma_body(lds, X0, ldx, Whi, Wlo, ldw, bias, C0, ldc, 0, 0, K, N, mode0, m0, n0);
    else
        dual_mfma_body(lds, X1, ldx, Whi, Wlo, ldw, bias, C1, ldc, 0, 0, K, N, mode1, m0, n0);
}

// ---------- zng + V2 fused: bx<4096 zng (R16-validated body, byte-identical);
//            bx>=4096: V2 = mask2 (.) (V1 @ Wh1^T) — backfills zng's drain tail ----------
__global__ __launch_bounds__(512, 4) void zng_v2(
    const unsigned short* __restrict__ WhF,    // [2][16][32][64][8] frag-packed Wh1,Wh2
    const unsigned short* __restrict__ WoF,    // [2][32][64][8] frag-packed Wout
    const unsigned short* __restrict__ G0F,    // [32][2][64][8] frag-packed G0
    const unsigned char* __restrict__ mz1,
    const unsigned char* __restrict__ mz2,
    const unsigned char* __restrict__ mz3,
    float* __restrict__ out,                   // (4096,192), writes cols 128..191
    const float* __restrict__ tA,              // V1 output (V2 input)
    const unsigned short* __restrict__ Wh1H, const unsigned short* __restrict__ Wh1L,
    const unsigned char* __restrict__ mt2,
    float* __restrict__ zA)                    // V2 output
{
    __shared__ __align__(16) unsigned char ldsb[66560];

    if (blockIdx.x >= 4096) {
        int idx = blockIdx.x - 4096;           // 0..255
        dual_mfma_body(ldsb, tA, 512, Wh1H, Wh1L, 512, 0, zA, 512, 0, mt2,
                       512, 512, 4 | 16, (idx & 31) * 128, (idx >> 5) * 64);
        return;
    }

    unsigned short* RtF = (unsigned short*)ldsb;            // 65536 B, fragment order
    unsigned char* m2s = ldsb + 65536;                      // 512 B
    unsigned char* m3s = ldsb + 66048;                      // 512 B

    const int b0  = blockIdx.x;     // one batch element per block
    const int tid = threadIdx.x;

    m2s[tid] = mz2[(size_t)b0 * 512 + tid];
    m3s[tid] = mz3[(size_t)b0 * 512 + tid];

    // ---- setup: RtF = frag(mask1 (.) G0^T); coalesced read + linear LDS write ----
    #pragma unroll
    for (int it = 0; it < 8; ++it) {
        int sl = it * 512 + tid;           // fragment slot 0..4095
        int ls = sl & 63;                  // lane within fragment
        int ks = sl >> 7;                  // k-step
        int k0 = ks * 16 + (ls >> 5) * 8;  // first k of this lane's 8 elems
        s8v g = *(const s8v*)(G0F + (size_t)sl * 8);
        const unsigned char* mm = mz1 + (size_t)b0 * 512 + k0;
        unsigned int mlo = *(const unsigned int*)(mm);
        unsigned int mhi = *(const unsigned int*)(mm + 4);
        s8v r;
        #pragma unroll
        for (int j = 0; j < 4; ++j) r[j] = ((mlo >> (8 * j)) & 1) ? g[j] : (short)0;
        #pragma unroll
        for (int j = 0; j < 4; ++j) r[4 + j] = ((mhi >> (8 * j)) & 1) ? g[4 + j] : (short)0;
        *(s8v*)(&RtF[(size_t)sl * 8]) = r;
    }
    __syncthreads();

    const int lane = tid & 63, wave = tid >> 6;
    const int l31 = lane & 31, h = lane >> 5;

    // ---- 2 chained layers: R <- mask (.) (Wh @ R) ----
    for (int s = 0; s < 2; ++s) {
        const unsigned short* Ar0 = WhF + (size_t)s * 262144
                                  + (size_t)(wave * 2) * 16384 + lane * 8;
        const unsigned short* Ar1 = Ar0 + 16384;

        f16v acc[2][2];
        #pragma unroll
        for (int mt = 0; mt < 2; ++mt)
            #pragma unroll
            for (int nt = 0; nt < 2; ++nt)
                acc[mt][nt] = (f16v)(0.0f);

        // 2-deep A prefetch (L2 ~200cyc), 1-deep B prefetch (LDS)
        s8v a0A = *(const s8v*)(Ar0);
        s8v a1A = *(const s8v*)(Ar1);
        s8v a0B = *(const s8v*)(Ar0 + 512);
        s8v a1B = *(const s8v*)(Ar1 + 512);
        s8v b0c = *(const s8v*)&RtF[lane * 8];
        s8v b1c = *(const s8v*)&RtF[512 + lane * 8];

        #pragma unroll 4
        for (int ks = 0; ks < 32; ++ks) {
            int kf = ((ks + 2) & 31) * 512;           // A: wraps; redundant tail loads
            s8v a0N = *(const s8v*)(Ar0 + kf);
            s8v a1N = *(const s8v*)(Ar1 + kf);
            int kb = ((ks + 1) & 31) * 1024;          // B: fragment-linear
            s8v b0n = *(const s8v*)&RtF[kb + lane * 8];
            s8v b1n = *(const s8v*)&RtF[kb + 512 + lane * 8];

            __builtin_amdgcn_s_setprio(1);
            acc[0][0] = __builtin_amdgcn_mfma_f32_32x32x16_bf16(a0A, b0c, acc[0][0], 0, 0, 0);
            acc[0][1] = __builtin_amdgcn_mfma_f32_32x32x16_bf16(a0A, b1c, acc[0][1], 0, 0, 0);
            acc[1][0] = __builtin_amdgcn_mfma_f32_32x32x16_bf16(a1A, b0c, acc[1][0], 0, 0, 0);
            acc[1][1] = __builtin_amdgcn_mfma_f32_32x32x16_bf16(a1A, b1c, acc[1][1], 0, 0, 0);
            __builtin_amdgcn_s_setprio(0);

            a0A = a0B; a0B = a0N;
            a1A = a1B; a1B = a1N;
            b0c = b0n; b1c = b1n;
        }
        __syncthreads();

        // ---- epilogue: mask, pack bf16, write new RtF (fragment order, conflict-free) ----
        const unsigned char* msk = (s == 0) ? m2s : m3s;
        #pragma unroll
        for (int mt = 0; mt < 2; ++mt) {
            #pragma unroll
            for (int g = 0; g < 4; ++g) {
                int kk = wave * 64 + mt * 32 + g * 8 + h * 4;   // output k-row base
                int ks = wave * 4 + mt * 2 + (g >> 1);
                int khalf = g & 1;
                uchar4 mv = *(const uchar4*)&msk[kk];
                unsigned char mb[4] = {mv.x, mv.y, mv.z, mv.w};
                #pragma unroll
                for (int nt = 0; nt < 2; ++nt) {
                    s4v pk;
                    #pragma unroll
                    for (int r = 0; r < 4; ++r) {
                        float v = mb[r] ? acc[mt][nt][g * 4 + r] : 0.0f;
                        pk[r] = (short)f2bf(v);
                    }
                    *(s4v*)(&RtF[(ks * 2 + nt) * 512 + (l31 + 32 * khalf) * 8 + h * 4]) = pk;
                }
            }
        }
        __syncthreads();
    }

    // ---- final: Wout @ R, row norms; waves 0-1 only (no barriers below) ----
    if (wave < 2) {
        const unsigned short* Wr = WoF + wave * 16384 + lane * 8;
        f16v a3[2];
        a3[0] = (f16v)(0.0f);
        a3[1] = (f16v)(0.0f);
        #pragma unroll 2
        for (int ks = 0; ks < 32; ++ks) {
            s8v af = *(const s8v*)(Wr + ks * 512);
            s8v bb0 = *(const s8v*)&RtF[ks * 1024 + lane * 8];
            s8v bb1 = *(const s8v*)&RtF[ks * 1024 + 512 + lane * 8];
            a3[0] = __builtin_amdgcn_mfma_f32_32x32x16_bf16(af, bb0, a3[0], 0, 0, 0);
            a3[1] = __builtin_amdgcn_mfma_f32_32x32x16_bf16(af, bb1, a3[1], 0, 0, 0);
        }
        // per-lane: rows wave*32 + g*8 + h*4 + r, cols (nt*32 + l31)
        float sq[16];
        #pragma unroll
        for (int i = 0; i < 16; ++i) {
            float v0 = a3[0][i], v1 = a3[1][i];
            sq[i] = fmaf(v0, v0, v1 * v1);
        }
        #pragma unroll
        for (int off = 1; off < 32; off <<= 1)
            #pragma unroll
            for (int i = 0; i < 16; ++i)
                sq[i] += __shfl_xor(sq[i], off, 64);
        if (l31 == 0) {
            #pragma unroll
            for (int g = 0; g < 4; ++g)
                #pragma unroll
                for (int r = 0; r < 4; ++r)
                    out[(size_t)b0 * 192 + 128 + wave * 32 + g * 8 + h * 4 + r] = sqrtf(sq[g * 4 + r]);
        }
    }
}

// ---------- host ----------
extern "C" void kernel_launch(void* const* d_in, const int* in_sizes, int n_in,
                              void* d_out, int out_size, void* d_ws, size_t ws_size,
                              hipStream_t stream) {
    const float* x    = (const float*)d_in[0];
    const float* Win  = (const float*)d_in[1];
    const float* bin  = (const float*)d_in[2];
    const float* Wh   = (const float*)d_in[3];
    const float* bh   = (const float*)d_in[4];
    const float* Wout = (const float*)d_in[5];
    const float* bout = (const float*)d_in[6];
    float* out = (float*)d_out;

    char* ws = (char*)d_ws;
    unsigned short* whi  = (unsigned short*)(ws);                   // 1703936 B
    unsigned short* wlo  = (unsigned short*)(ws + 1703936);         // 1703936 B
    unsigned short* G0hi = (unsigned short*)(ws + 3407872);         // 65536 B
    unsigned short* G0lo = (unsigned short*)(ws + 3473408);         // 65536 B
    unsigned short* G0F  = (unsigned short*)(ws + 3538944);         // 65536 B (frag-packed)
    unsigned char*  masks = (unsigned char*)(ws + 3604480);         // 6 * 2 MB
    unsigned char* mt1 = masks + 0 * 2097152;
    unsigned char* mt2 = masks + 1 * 2097152;
    unsigned char* mt3 = masks + 2 * 2097152;
    unsigned char* mz1 = masks + 3 * 2097152;
    unsigned char* mz2 = masks + 4 * 2097152;
    unsigned char* mz3 = masks + 5 * 2097152;
    float* bufs = (float*)(ws + 3604480 + 12582912);                // 4 x 8 MB
    float* tA = bufs + 0 * 2097152;
    float* tB = bufs + 1 * 2097152;
    float* zA = bufs + 2 * 2097152;
    float* zB = bufs + 3 * 2097152;
    unsigned short* WhF = (unsigned short*)(ws + 49741824);         // 1048576 B
    unsigned short* WoF = (unsigned short*)(ws + 50790400);         // 65536 B

    // hi/lo plane offsets (elems): [Win@0 | Wh0@32768 | Wh1@294912 | Wh2@557056 | Wout@819200]
    const unsigned short* WinH  = whi,          *WinL  = wlo;
    const unsigned short* Wh0H  = whi + 32768,  *Wh0L  = wlo + 32768;
    const unsigned short* Wh1H  = whi + 294912, *Wh1L  = wlo + 294912;
    const unsigned short* Wh2H  = whi + 557056, *Wh2L  = wlo + 557056;
    const unsigned short* WoutH = whi + 819200, *WoutL = wlo + 819200;

    const float* Wh0 = Wh;
    const float* Wh1 = Wh + 262144;
    const float* Wh2 = Wh + 524288;
    const float* bh0 = bh, *bh1 = bh + 512, *bh2 = bh + 1024;

    // ---- setup (2 dispatches, was 3) ----
    conv_g0<<<dim3(3456), dim3(256), 0, stream>>>(Win, Wh, Wout, whi, wlo, G0hi, G0lo, G0F);
    h0_pack<<<dim3(32, 8, 3), dim3(512), 0, stream>>>(x, Win, WinH, WinL, bin, tA, zA,
                                                      whi, WhF, WoF);                              // h0 + frag_pack

    // ---- forward + delta chain (t fp32 for mask fidelity; z split-bf16 MFMA) ----
    gemm_dualM<<<dim3(32, 8, 2), dim3(512), 0, stream>>>(tA, zA, 512, Wh0, 512, Wh0H, Wh0L, bh0,
                                                         tB, zB, 512, 0, 0, 512, 512, 1 | 2 | 4);  // h1
    gemm_dual4<<<dim3(32, 8, 4), dim3(512), 0, stream>>>(tB, zB, 512, Wh1, Wh0, 512,
                                                         Wh1H, Wh1L, Wh0H, Wh0L, bh1, bh0,
                                                         tA, zA, 512, mt1, mz1, 512, 512);         // h2 + delta1
    gemm_dual4<<<dim3(32, 8, 4), dim3(512), 0, stream>>>(tA, zA, 512, Wh2, Wh1, 512,
                                                         Wh2H, Wh2L, Wh1H, Wh1L, bh2, bh1,
                                                         tB, zB, 512, mt2, mz2, 512, 512);         // h3 + delta2
    d3v1<<<dim3(32, 8, 3), dim3(512), 0, stream>>>(tB, zB, x, Wh2, Wh2H, Wh2L, G0hi, G0lo,
                                                   bh2, tA, mt3, mz3, mt1);                        // delta3 + V1

    // ---- zng (4096 blocks) + V2 (256 tail blocks, backfill) ----
    zng_v2<<<dim3(4352), dim3(512), 0, stream>>>(WhF, WoF, G0F, mz1, mz2, mz3, out,
                                                 tA, Wh1H, Wh1L, mt2, zA);

    // ---- V3 ----
    gemm_m1<<<dim3(32, 8), dim3(512), 0, stream>>>(zA, 512, Wh2H, Wh2L, 512, zB, 512,
                                                   mt3, 512, 512, 4 | 16);                         // V3

    // ---- fused finals: h_out (t, cols 0..63, +bias) + h_dot (V3, cols 64..127) ----
    gemm_mm<<<dim3(32, 1, 2), dim3(512), 0, stream>>>(tB, zB, 512, WoutH, WoutL, 512, bout,
                                                      out, out + 64, 192, 512, 64, 1 | 4, 4);
}